// Round 8
// baseline (1348.504 us; speedup 1.0000x reference)
//
#include <hip/hip_runtime.h>
#include <hip/hip_bf16.h>

// TreeLSTM on MI355X. B=256 trees, 256 leaves (depth 9), H=512, C=5.
// f32 I/O; bf16 MFMA; f32 cell state. Output f32 [256,511,5].
//
// R26 = R25 (783.8us) with leaf128/level128 K-loops coarsened to SUPER-STEPS:
// same R20 fence semantics, K=64 per phase (both dbuf halves as one tile):
//   [top FENCE_VM(0): this ss's 2 tiles landed (cover = prev 80-MFMA phase)]
//   [26 ds_read frags] [FENCE_LGKM: all waves consumed bufs] [refill 14 DMA]
//   [setprio 80 MFMA]
// Barriers per 64-K: 2 (was 4). R25 evidence: 2 blocks/CU pinned (occupancy
// 20.5% regardless of 48KB LDS), wall 4060cy/K-step vs 1552 MFMA + 1280 LDS
// -> residual is per-phase sync rendezvous -> amortize it (m218/m201 lesson).
// vmcnt(0)-at-top drains loads with full-MFMA-phase cover (NOT R21's fresh-
// load drain). VGPR ~175 fits (256,2), no spill. Same K accumulation order.
// level_kernel / logits / cvt / host: verbatim R25.

typedef __bf16 bf16;
typedef bf16  bf16x8 __attribute__((ext_vector_type(8)));
typedef float f32x4  __attribute__((ext_vector_type(4)));

__device__ __forceinline__ float sigm(float x){ return 1.0f/(1.0f + __expf(-x)); }
__device__ __forceinline__ float tanh_f(float x){ return 1.0f - 2.0f/(__expf(2.0f*x)+1.0f); }

// async global->LDS, 16 bytes per lane. HW dest = wave-uniform base + lane*16.
__device__ __forceinline__ void gload16(const bf16* g, bf16* l){
  __builtin_amdgcn_global_load_lds(
      (const __attribute__((address_space(1))) void*)g,
      (__attribute__((address_space(3))) void*)l, 16, 0, 0);
}

// vmcnt(N) then barrier: own older DMAs landed; newest stay in flight.
#define FENCE_VM(N) do{ asm volatile("s_waitcnt vmcnt(" #N ")" ::: "memory"); \
  __builtin_amdgcn_sched_barrier(0); __builtin_amdgcn_s_barrier(); \
  __builtin_amdgcn_sched_barrier(0); }while(0)
// barrier that only certifies LDS reads landed in regs (no VMEM drain)
#define FENCE_LGKM do{ asm volatile("s_waitcnt lgkmcnt(0)" ::: "memory"); \
  __builtin_amdgcn_sched_barrier(0); __builtin_amdgcn_s_barrier(); \
  __builtin_amdgcn_sched_barrier(0); }while(0)

// ---- merged converts: Wpad | embp | Uall in one dispatch (proven R17) ----
__global__ void cvt_all(const float* __restrict__ Wiou, const float* __restrict__ Uiou,
                        const float* __restrict__ Uf, const float* __restrict__ emb,
                        bf16* __restrict__ Wpad, bf16* __restrict__ Uall,
                        bf16* __restrict__ embp){
  const int b = blockIdx.x, t = threadIdx.x;            // 320 threads
  if (b < 1536){
    Wpad[b*320 + t] = (bf16)(t < 300 ? Wiou[b*300 + t] : 0.f);
  } else if (b < 1536 + 32000){
    const int r = b - 1536;
    embp[(size_t)r*320 + t] = (bf16)(t < 300 ? emb[(size_t)r*300 + t] : 0.f);
  } else {
    const size_t i = (size_t)(b - 33536)*320 + t;       // 8192 blocks * 320 = 2560*1024
    if (i < (size_t)1536*1024) Uall[i] = (bf16)Uiou[i];
    else                       Uall[i] = (bf16)Uf[i - (size_t)1536*1024];
  }
}

// ---- leaf BM=128: super-step K=64, 2 barriers per 64-K (R26) ----
__global__ __launch_bounds__(256, 2)
void leaf128_kernel(const int* __restrict__ wordid, const bf16* __restrict__ embp,
                    const bf16* __restrict__ Wpad, const float* __restrict__ Wb,
                    bf16* __restrict__ hcur, float* __restrict__ ccur)
{
  __shared__ bf16 lsA[2][128*32];
  __shared__ bf16 lsB[2][192*32];
  const int t = threadIdx.x;
  const int mrow0 = blockIdx.x*128, nblk = blockIdx.y*64;
  const int lane16 = t&15, quad = (t&63)>>4, w = t>>6;

  const int lrow = t>>2;                                 // 0..63
  const int qsw  = ((t&3) ^ ((t>>3)&3))*8;               // swizzled src k-chunk (elems)
  const int wb   = (t & 192)*8;                          // wave-uniform LDS dest base

  const int wid0 = wordid[mrow0 + lrow];
  const int wid1 = wordid[mrow0 + 64 + lrow];
  const bf16* srcA0 = embp + (size_t)wid0*320 + qsw;
  const bf16* srcA1 = embp + (size_t)wid1*320 + qsw;
  const bf16* srcB0 = Wpad + (size_t)(0*512 + nblk + lrow)*320 + qsw;
  const bf16* srcB1 = Wpad + (size_t)(1*512 + nblk + lrow)*320 + qsw;
  const bf16* srcB2 = Wpad + (size_t)(2*512 + nblk + lrow)*320 + qsw;

  const int sA   = (t>>1)&3;
  const int aoff = lane16*32 + ((quad ^ sA)*8);          // + rt*512
  const int boff = (w*16 + lane16)*32 + ((quad ^ sA)*8); // + g*2048

#define LEAF_DMA(buf, k0) do{ \
  gload16(srcA0 + (k0), lsA[buf] + wb);        gload16(srcA1 + (k0), lsA[buf] + 2048 + wb); \
  gload16(srcB0 + (k0), lsB[buf] + wb);        gload16(srcB1 + (k0), lsB[buf] + 2048 + wb); \
  gload16(srcB2 + (k0), lsB[buf] + 4096 + wb); }while(0)

  f32x4 acc[3][8];
  const f32x4 zero = {0.f,0.f,0.f,0.f};
  #pragma unroll
  for(int o=0;o<3;o++){
    #pragma unroll
    for(int rt=0;rt<8;rt++) acc[o][rt]=zero;
  }

  // prologue: super-tile 0 (k-tiles 0,1) in flight
  LEAF_DMA(0, 0); LEAF_DMA(1, 32);

  for (int ss = 0; ss < 5; ss++){
    FENCE_VM(0);                              // this ss's 2 tiles landed (covered)
    bf16x8 fB[3], fA[8], gB[3], gA[8];
    #pragma unroll
    for(int g=0;g<3;g++) fB[g] = *(const bf16x8*)&lsB[0][g*2048 + boff];
    #pragma unroll
    for(int rt=0;rt<8;rt++) fA[rt] = *(const bf16x8*)&lsA[0][rt*512 + aoff];
    #pragma unroll
    for(int g=0;g<3;g++) gB[g] = *(const bf16x8*)&lsB[1][g*2048 + boff];
    #pragma unroll
    for(int rt=0;rt<8;rt++) gA[rt] = *(const bf16x8*)&lsA[1][rt*512 + aoff];
    if (ss < 4){
      FENCE_LGKM;                             // all waves consumed both bufs
      LEAF_DMA(0, ss*64 + 64); LEAF_DMA(1, ss*64 + 96);
    }
    __builtin_amdgcn_s_setprio(1);
    #pragma unroll
    for(int rt=0;rt<8;rt++){
      #pragma unroll
      for(int g=0;g<3;g++)
        acc[g][rt] = __builtin_amdgcn_mfma_f32_16x16x32_bf16(fA[rt], fB[g], acc[g][rt], 0,0,0);
    }
    #pragma unroll
    for(int rt=0;rt<8;rt++){
      #pragma unroll
      for(int g=0;g<3;g++)
        acc[g][rt] = __builtin_amdgcn_mfma_f32_16x16x32_bf16(gA[rt], gB[g], acc[g][rt], 0,0,0);
    }
    __builtin_amdgcn_s_setprio(0);
  }
  const int j = nblk + w*16 + lane16;
  const float bi=Wb[j], bo=Wb[512+j], bu=Wb[1024+j];
  #pragma unroll
  for(int rt=0;rt<8;rt++){
    #pragma unroll
    for(int reg=0;reg<4;reg++){
      const int row = mrow0 + rt*16 + quad*4 + reg;   // C/D: row=quad*4+reg, col=lane16
      float iv=acc[0][rt][reg]+bi, ov=acc[1][rt][reg]+bo, uv=acc[2][rt][reg]+bu;
      float c = sigm(iv)*tanh_f(uv);
      float h = sigm(ov)*tanh_f(c);
      ccur[(size_t)row*512 + j] = c;
      hcur[(size_t)row*512 + j] = (bf16)h;
    }
  }
#undef LEAF_DMA
}

// ---- level BM=64: R20 schedule at 48KB LDS, 3 blocks/CU (R23, proven) ----
__global__ __launch_bounds__(256, 3)
void level_kernel(const bf16* __restrict__ hprev, bf16* __restrict__ hcur,
                  const float* __restrict__ cprev, float* __restrict__ ccur,
                  const bf16* __restrict__ Uall, const float* __restrict__ Uioub,
                  const float* __restrict__ Ufb)
{
  __shared__ bf16 lsA[2][64*32];
  __shared__ bf16 lsB[2][320*32];
  const int t = threadIdx.x;
  const int mrow0 = blockIdx.x*64, nblk = blockIdx.y*64;
  const int lane16 = t&15, quad = (t&63)>>4, w = t>>6;

  const int lrow = t>>2;                                 // 0..63
  const int qsw  = ((t&3) ^ ((t>>3)&3))*8;               // swizzled src k-chunk (elems)
  const int wb   = (t & 192)*8;                          // wave-uniform LDS dest base

  const bf16* srcA0 = hprev + (size_t)(mrow0 + lrow)*1024 + qsw;
  const bf16* srcB0 = Uall + (size_t)(0*512 + nblk + lrow)*1024 + qsw;
  const bf16* srcB1 = Uall + (size_t)(1*512 + nblk + lrow)*1024 + qsw;
  const bf16* srcB2 = Uall + (size_t)(2*512 + nblk + lrow)*1024 + qsw;
  const bf16* srcB3 = Uall + (size_t)(3*512 + nblk + lrow)*1024 + qsw;
  const bf16* srcB4 = Uall + (size_t)(4*512 + nblk + lrow)*1024 + qsw;

  const int sA   = (t>>1)&3;
  const int aoff = lane16*32 + ((quad ^ sA)*8);          // + rt*512
  const int boff = (w*16 + lane16)*32 + ((quad ^ sA)*8); // + g*2048

#define LV64_DMA(buf, k0) do{ \
  gload16(srcA0 + (k0), lsA[buf] + wb); \
  gload16(srcB0 + (k0), lsB[buf] + wb);        gload16(srcB1 + (k0), lsB[buf] + 2048 + wb); \
  gload16(srcB2 + (k0), lsB[buf] + 4096 + wb); gload16(srcB3 + (k0), lsB[buf] + 6144 + wb); \
  gload16(srcB4 + (k0), lsB[buf] + 8192 + wb); }while(0)

  f32x4 acc[5][4];
  const f32x4 zero = {0.f,0.f,0.f,0.f};
  #pragma unroll
  for(int o=0;o<5;o++){
    #pragma unroll
    for(int rt=0;rt<4;rt++) acc[o][rt]=zero;
  }

  // prologue: tiles 0 and 1 in flight; wait tile 0 (oldest 6), keep tile 1 flying
  LV64_DMA(0, 0); LV64_DMA(1, 32);
  FENCE_VM(6);

  for (int ks = 0; ks < 32; ks++){
    const int cur = ks & 1;
    bf16x8 bfrag[5], afrag[4];
    #pragma unroll
    for(int g=0;g<5;g++) bfrag[g] = *(const bf16x8*)&lsB[cur][g*2048 + boff];
    #pragma unroll
    for(int rt=0;rt<4;rt++) afrag[rt] = *(const bf16x8*)&lsA[cur][rt*512 + aoff];
    FENCE_LGKM;                               // frags in regs; buf[cur] free
    if (ks < 30){
      LV64_DMA(cur, (ks+2)*32);
    }
    __builtin_amdgcn_s_setprio(1);
    #pragma unroll
    for(int rt=0;rt<4;rt++){
      #pragma unroll
      for(int g=0;g<5;g++)
        acc[g][rt] = __builtin_amdgcn_mfma_f32_16x16x32_bf16(afrag[rt], bfrag[g], acc[g][rt], 0,0,0);
    }
    __builtin_amdgcn_s_setprio(0);
    if (ks < 30)       FENCE_VM(6);           // tile ks+1 done; ks+2 stays in flight
    else if (ks < 31)  FENCE_VM(0);           // tail: drain last tile
  }

  const int j = nblk + w*16 + lane16;
  const float bi =Uioub[j], bo=Uioub[512+j], bu=Uioub[1024+j];
  const float bfl=Ufb[j],   bfr=Ufb[512+j];
  #pragma unroll
  for(int rt=0;rt<4;rt++){
    #pragma unroll
    for(int reg=0;reg<4;reg++){
      const int row = mrow0 + rt*16 + quad*4 + reg;
      float iv=acc[0][rt][reg]+bi, ov=acc[1][rt][reg]+bo, uv=acc[2][rt][reg]+bu;
      float fl=acc[3][rt][reg]+bfl, fr=acc[4][rt][reg]+bfr;
      float cl = cprev[((size_t)row*2  )*512 + j];
      float cr = cprev[((size_t)row*2+1)*512 + j];
      float cf = sigm(fl)*cl + sigm(fr)*cr;
      float c  = sigm(iv)*tanh_f(uv) + cf;
      float h  = sigm(ov)*tanh_f(c);
      ccur[(size_t)row*512 + j] = c;
      hcur[(size_t)row*512 + j] = (bf16)h;
    }
  }
#undef LV64_DMA
}

// ---- level BM=128: super-step K=64, 2 barriers per 64-K (R26) ----
__global__ __launch_bounds__(256, 2)
void level128_kernel(const bf16* __restrict__ hprev, bf16* __restrict__ hcur,
                     const float* __restrict__ cprev, float* __restrict__ ccur,
                     const bf16* __restrict__ Uall, const float* __restrict__ Uioub,
                     const float* __restrict__ Ufb)
{
  __shared__ bf16 lsA[2][128*32];
  __shared__ bf16 lsB[2][320*32];
  const int t = threadIdx.x;
  const int mrow0 = blockIdx.x*128, nblk = blockIdx.y*64;
  const int lane16 = t&15, quad = (t&63)>>4, w = t>>6;

  const int lrow = t>>2;                                 // 0..63
  const int qsw  = ((t&3) ^ ((t>>3)&3))*8;               // swizzled src k-chunk (elems)
  const int wb   = (t & 192)*8;                          // wave-uniform LDS dest base

  const bf16* srcA0 = hprev + (size_t)(mrow0 + lrow)*1024 + qsw;
  const bf16* srcA1 = hprev + (size_t)(mrow0 + 64 + lrow)*1024 + qsw;
  const bf16* srcB0 = Uall + (size_t)(0*512 + nblk + lrow)*1024 + qsw;
  const bf16* srcB1 = Uall + (size_t)(1*512 + nblk + lrow)*1024 + qsw;
  const bf16* srcB2 = Uall + (size_t)(2*512 + nblk + lrow)*1024 + qsw;
  const bf16* srcB3 = Uall + (size_t)(3*512 + nblk + lrow)*1024 + qsw;
  const bf16* srcB4 = Uall + (size_t)(4*512 + nblk + lrow)*1024 + qsw;

  const int sA   = (t>>1)&3;
  const int aoff = lane16*32 + ((quad ^ sA)*8);          // + rt*512
  const int boff = (w*16 + lane16)*32 + ((quad ^ sA)*8); // + g*2048

#define LVL_DMA(buf, k0) do{ \
  gload16(srcA0 + (k0), lsA[buf] + wb);        gload16(srcA1 + (k0), lsA[buf] + 2048 + wb); \
  gload16(srcB0 + (k0), lsB[buf] + wb);        gload16(srcB1 + (k0), lsB[buf] + 2048 + wb); \
  gload16(srcB2 + (k0), lsB[buf] + 4096 + wb); gload16(srcB3 + (k0), lsB[buf] + 6144 + wb); \
  gload16(srcB4 + (k0), lsB[buf] + 8192 + wb); }while(0)

  f32x4 acc[5][8];
  const f32x4 zero = {0.f,0.f,0.f,0.f};
  #pragma unroll
  for(int o=0;o<5;o++){
    #pragma unroll
    for(int rt=0;rt<8;rt++) acc[o][rt]=zero;
  }

  // prologue: super-tile 0 (k-tiles 0,1) in flight
  LVL_DMA(0, 0); LVL_DMA(1, 32);

  for (int ss = 0; ss < 16; ss++){
    FENCE_VM(0);                              // this ss's 2 tiles landed (covered
                                              // by previous ss's 80-MFMA phase)
    bf16x8 fB[5], fA[8], gB[5], gA[8];
    #pragma unroll
    for(int g=0;g<5;g++) fB[g] = *(const bf16x8*)&lsB[0][g*2048 + boff];
    #pragma unroll
    for(int rt=0;rt<8;rt++) fA[rt] = *(const bf16x8*)&lsA[0][rt*512 + aoff];
    #pragma unroll
    for(int g=0;g<5;g++) gB[g] = *(const bf16x8*)&lsB[1][g*2048 + boff];
    #pragma unroll
    for(int rt=0;rt<8;rt++) gA[rt] = *(const bf16x8*)&lsA[1][rt*512 + aoff];
    if (ss < 15){
      FENCE_LGKM;                             // all waves consumed both bufs
      LVL_DMA(0, ss*64 + 64); LVL_DMA(1, ss*64 + 96);
    }
    __builtin_amdgcn_s_setprio(1);
    #pragma unroll
    for(int rt=0;rt<8;rt++){
      #pragma unroll
      for(int g=0;g<5;g++)
        acc[g][rt] = __builtin_amdgcn_mfma_f32_16x16x32_bf16(fA[rt], fB[g], acc[g][rt], 0,0,0);
    }
    #pragma unroll
    for(int rt=0;rt<8;rt++){
      #pragma unroll
      for(int g=0;g<5;g++)
        acc[g][rt] = __builtin_amdgcn_mfma_f32_16x16x32_bf16(gA[rt], gB[g], acc[g][rt], 0,0,0);
    }
    __builtin_amdgcn_s_setprio(0);
  }

  const int j = nblk + w*16 + lane16;
  const float bi =Uioub[j], bo=Uioub[512+j], bu=Uioub[1024+j];
  const float bfl=Ufb[j],   bfr=Ufb[512+j];
  #pragma unroll
  for(int rt=0;rt<8;rt++){
    #pragma unroll
    for(int reg=0;reg<4;reg++){
      const int row = mrow0 + rt*16 + quad*4 + reg;
      float iv=acc[0][rt][reg]+bi, ov=acc[1][rt][reg]+bo, uv=acc[2][rt][reg]+bu;
      float fl=acc[3][rt][reg]+bfl, fr=acc[4][rt][reg]+bfr;
      float cl = cprev[((size_t)row*2  )*512 + j];
      float cr = cprev[((size_t)row*2+1)*512 + j];
      float cf = sigm(fl)*cl + sigm(fr)*cr;
      float c  = sigm(iv)*tanh_f(uv) + cf;
      float h  = sigm(ov)*tanh_f(c);
      ccur[(size_t)row*512 + j] = c;
      hcur[(size_t)row*512 + j] = (bf16)h;
    }
  }
#undef LVL_DMA
}

// ---- logits (verbatim GEMV, proven): single-level version for leaf chunks ----
__global__ __launch_bounds__(256)
void logits_kernel(const bf16* __restrict__ h, const float* __restrict__ linw,
                   const float* __restrict__ linb, float* __restrict__ out,
                   int rowbase, int lgm, int mask, int off){
  const int row = blockIdx.x*4 + (threadIdx.x>>6);
  const int l = threadIdx.x & 63;
  bf16x8 hv = *(const bf16x8*)(h + (size_t)row*512 + l*8);
  float hf[8];
  #pragma unroll
  for(int jj=0;jj<8;jj++) hf[jj] = (float)hv[jj];
  float s[5];
  #pragma unroll
  for(int c=0;c<5;c++){
    const f32x4 w0 = *(const f32x4*)(linw + c*512 + l*8);
    const f32x4 w1 = *(const f32x4*)(linw + c*512 + l*8 + 4);
    float a = 0.f;
    #pragma unroll
    for(int jj=0;jj<4;jj++) a += hf[jj]*w0[jj] + hf[4+jj]*w1[jj];
    s[c]=a;
  }
  #pragma unroll
  for(int o=32;o>0;o>>=1){
    #pragma unroll
    for(int c=0;c<5;c++) s[c] += __shfl_down(s[c], o, 64);
  }
  if (l==0){
    const int g = rowbase + row;
    const int node = (g>>lgm)*511 + off + (g&mask);
    #pragma unroll
    for(int c=0;c<5;c++) out[(size_t)node*5+c] = s[c] + linb[c];
  }
}

// ---- logits2: two levels in one dispatch (same GEMV; per-row source select) ----
__global__ __launch_bounds__(256)
void logits2_kernel(const bf16* __restrict__ ha, int rows_a, int lgm_a, int mask_a, int off_a,
                    const bf16* __restrict__ hb, int lgm_b, int mask_b, int off_b,
                    const float* __restrict__ linw, const float* __restrict__ linb,
                    float* __restrict__ out){
  const int row = blockIdx.x*4 + (threadIdx.x>>6);
  const int l = threadIdx.x & 63;
  const bf16* hrow; int g, lgm, mask, off;
  if (row < rows_a){ hrow = ha + (size_t)row*512;            g = row;           lgm=lgm_a; mask=mask_a; off=off_a; }
  else             { hrow = hb + (size_t)(row-rows_a)*512;   g = row - rows_a;  lgm=lgm_b; mask=mask_b; off=off_b; }
  bf16x8 hv = *(const bf16x8*)(hrow + l*8);
  float hf[8];
  #pragma unroll
  for(int jj=0;jj<8;jj++) hf[jj] = (float)hv[jj];
  float s[5];
  #pragma unroll
  for(int c=0;c<5;c++){
    const f32x4 w0 = *(const f32x4*)(linw + c*512 + l*8);
    const f32x4 w1 = *(const f32x4*)(linw + c*512 + l*8 + 4);
    float a = 0.f;
    #pragma unroll
    for(int jj=0;jj<4;jj++) a += hf[jj]*w0[jj] + hf[4+jj]*w1[jj];
    s[c]=a;
  }
  #pragma unroll
  for(int o=32;o>0;o>>=1){
    #pragma unroll
    for(int c=0;c<5;c++) s[c] += __shfl_down(s[c], o, 64);
  }
  if (l==0){
    const int node = (g>>lgm)*511 + off + (g&mask);
    #pragma unroll
    for(int c=0;c<5;c++) out[(size_t)node*5+c] = s[c] + linb[c];
  }
}

__global__ void zero_out(float* out, int n){
  int i = blockIdx.x*256 + threadIdx.x;
  if (i < n) out[i] = 0.f;
}

extern "C" void kernel_launch(void* const* d_in, const int* in_sizes, int n_in,
                              void* d_out, int out_size, void* d_ws, size_t ws_size,
                              hipStream_t stream)
{
  const int*   wordid = (const int*)d_in[0];
  const float* emb    = (const float*)d_in[1];
  const float* Wiou   = (const float*)d_in[2];
  const float* Wioub  = (const float*)d_in[3];
  const float* Uiou   = (const float*)d_in[4];
  const float* Uioub  = (const float*)d_in[5];
  const float* Uf     = (const float*)d_in[6];
  const float* Ufb    = (const float*)d_in[7];
  const float* linw   = (const float*)d_in[8];
  const float* linb   = (const float*)d_in[9];
  float* out = (float*)d_out;

  // ---- fixed-region layout (R7/R14) ----
  const size_t oWPD  = 0;
  const size_t oUALL = oWPD  + (size_t)1536*320*2;
  const size_t oEMB  = oUALL + (size_t)2560*1024*2;
  const size_t oH1   = oEMB  + (size_t)32000*320*2;
  const size_t oC1   = oH1   + (size_t)32768*512*2;
  const size_t oH0   = oC1   + (size_t)32768*512*4;
  size_t R0 = 0;
  {
    const size_t t2 = oH0 + (size_t)32768*512*(2+4);   // 228.0 MB
    const size_t t4 = oH0 + (size_t)16384*512*(2+4);   // 177.7 MB
    const size_t t8 = oH0 + (size_t) 8192*512*(2+4);   // 152.5 MB
    if      (ws_size >= t2) R0 = 32768;
    else if (ws_size >= t4) R0 = 16384;
    else if (ws_size >= t8) R0 = 8192;
  }
  if (R0 == 0){
    zero_out<<<(out_size+255)/256, 256, 0, stream>>>(out, out_size);
    return;
  }

  char* ws = (char*)d_ws;
  bf16*  Wpad = (bf16*)(ws + oWPD);
  bf16*  Uall = (bf16*)(ws + oUALL);
  bf16*  embp = (bf16*)(ws + oEMB);
  bf16*  h1   = (bf16*)(ws + oH1);
  float* c1   = (float*)(ws + oC1);
  bf16*  h0   = (bf16*)(ws + oH0);
  float* c0   = (float*)(ws + oH0 + R0*1024);

  cvt_all<<<41728, 320, 0, stream>>>(Wiou, Uiou, Uf, emb, Wpad, Uall, embp);

  const int offs[9] = {0,256,384,448,480,496,504,508,510};
  const int nchunk = (int)(65536 / R0);

  // ---- leaf + level-1, chunked through h0/c0 scratch (leaf logits per chunk) ----
  for (int ch = 0; ch < nchunk; ch++){
    const int* wid = wordid + (size_t)ch*R0;
    leaf128_kernel<<<dim3((int)(R0/128), 8), 256, 0, stream>>>(wid, embp, Wpad, Wioub,
                                                               h0, c0);
    logits_kernel<<<(int)(R0/4), 256, 0, stream>>>(h0, linw, linb, out,
                                                   (int)(ch*R0), 8, 255, 0);
    bf16*  h1c = h1 + (size_t)ch*(R0/2)*512;
    float* c1c = c1 + (size_t)ch*(R0/2)*512;
    const int orows = (int)(R0/2);
    level128_kernel<<<dim3(orows/128, 8), 256, 0, stream>>>(h0, h1c, c0, c1c,
                                                            Uall, Uioub, Ufb);
  }

  // ---- levels 2..8; after each EVEN level, one logits2 covers (lv-1, lv) ----
  // Validity: lv-1's h (h1) is intact until lv+1 writes h1; lv's h (h0) until lv+2.
  for (int lv = 2; lv <= 8; lv++){
    const int rows = 65536 >> lv;
    const bf16*  hin  = (lv & 1) ? h0 : h1;
    bf16*        hout = (lv & 1) ? h1 : h0;
    const float* cin  = (lv & 1) ? c0 : c1;
    float*       cout = (lv & 1) ? c1 : c0;
    if (rows >= 8192)
      level128_kernel<<<dim3(rows/128, 8), 256, 0, stream>>>(hin, hout, cin, cout,
                                                             Uall, Uioub, Ufb);
    else
      level_kernel<<<dim3(rows/64, 8), 256, 0, stream>>>(hin, hout, cin, cout,
                                                         Uall, Uioub, Ufb);
    if ((lv & 1) == 0){
      const int rows_a = 65536 >> (lv-1);        // lv-1 rows (in h1)
      const int rows_b = rows;                   // lv rows   (in h0)
      logits2_kernel<<<(rows_a + rows_b)/4, 256, 0, stream>>>(
          h1, rows_a, 8-(lv-1), (256>>(lv-1))-1, offs[lv-1],
          h0,         8-lv,     (256>>lv)-1,     offs[lv],
          linw, linb, out);
    }
  }
}

// Round 9
// 898.517 us; speedup vs baseline: 1.5008x; 1.5008x over previous
//
#include <hip/hip_runtime.h>
#include <hip/hip_bf16.h>

// TreeLSTM on MI355X. B=256 trees, 256 leaves (depth 9), H=512, C=5.
// f32 I/O; bf16 MFMA; f32 cell state. Output f32 [256,511,5].
//
// R27 = R25 (783.8us best) with a ZERO-NEW-CODE host-side A/B: big levels
// (lv1/lv2/lv3) routed through level_kernel (BM=64, 48KB LDS, (256,3) ->
// TRUE 3 blocks/CU, proven R23) instead of level128 (BM=128, 2 blocks/CU
// pinned). Tests whether 3 independent barrier groups pack MFMA/LDS pipes
// better than 2 bigger ones. R26 lesson (3rd spill): >13 live frags spills
// regardless of launch_bounds -- schedule granularity is register-capped.
// Both compute kernels verbatim R25. level128 kept (unused fallback).

typedef __bf16 bf16;
typedef bf16  bf16x8 __attribute__((ext_vector_type(8)));
typedef float f32x4  __attribute__((ext_vector_type(4)));

__device__ __forceinline__ float sigm(float x){ return 1.0f/(1.0f + __expf(-x)); }
__device__ __forceinline__ float tanh_f(float x){ return 1.0f - 2.0f/(__expf(2.0f*x)+1.0f); }

// async global->LDS, 16 bytes per lane. HW dest = wave-uniform base + lane*16.
__device__ __forceinline__ void gload16(const bf16* g, bf16* l){
  __builtin_amdgcn_global_load_lds(
      (const __attribute__((address_space(1))) void*)g,
      (__attribute__((address_space(3))) void*)l, 16, 0, 0);
}

// vmcnt(N) then barrier: own older DMAs landed; newest stay in flight.
#define FENCE_VM(N) do{ asm volatile("s_waitcnt vmcnt(" #N ")" ::: "memory"); \
  __builtin_amdgcn_sched_barrier(0); __builtin_amdgcn_s_barrier(); \
  __builtin_amdgcn_sched_barrier(0); }while(0)
// barrier that only certifies LDS reads landed in regs (no VMEM drain)
#define FENCE_LGKM do{ asm volatile("s_waitcnt lgkmcnt(0)" ::: "memory"); \
  __builtin_amdgcn_sched_barrier(0); __builtin_amdgcn_s_barrier(); \
  __builtin_amdgcn_sched_barrier(0); }while(0)

// ---- merged converts: Wpad | embp | Uall in one dispatch (proven R17) ----
__global__ void cvt_all(const float* __restrict__ Wiou, const float* __restrict__ Uiou,
                        const float* __restrict__ Uf, const float* __restrict__ emb,
                        bf16* __restrict__ Wpad, bf16* __restrict__ Uall,
                        bf16* __restrict__ embp){
  const int b = blockIdx.x, t = threadIdx.x;            // 320 threads
  if (b < 1536){
    Wpad[b*320 + t] = (bf16)(t < 300 ? Wiou[b*300 + t] : 0.f);
  } else if (b < 1536 + 32000){
    const int r = b - 1536;
    embp[(size_t)r*320 + t] = (bf16)(t < 300 ? emb[(size_t)r*300 + t] : 0.f);
  } else {
    const size_t i = (size_t)(b - 33536)*320 + t;       // 8192 blocks * 320 = 2560*1024
    if (i < (size_t)1536*1024) Uall[i] = (bf16)Uiou[i];
    else                       Uall[i] = (bf16)Uf[i - (size_t)1536*1024];
  }
}

// ---- leaf BM=128: gload_lds + counted-vmcnt depth-2 + setprio (R20, proven) ----
__global__ __launch_bounds__(256, 2)
void leaf128_kernel(const int* __restrict__ wordid, const bf16* __restrict__ embp,
                    const bf16* __restrict__ Wpad, const float* __restrict__ Wb,
                    bf16* __restrict__ hcur, float* __restrict__ ccur)
{
  __shared__ bf16 lsA[2][128*32];
  __shared__ bf16 lsB[2][192*32];
  const int t = threadIdx.x;
  const int mrow0 = blockIdx.x*128, nblk = blockIdx.y*64;
  const int lane16 = t&15, quad = (t&63)>>4, w = t>>6;

  const int lrow = t>>2;                                 // 0..63
  const int qsw  = ((t&3) ^ ((t>>3)&3))*8;               // swizzled src k-chunk (elems)
  const int wb   = (t & 192)*8;                          // wave-uniform LDS dest base

  const int wid0 = wordid[mrow0 + lrow];
  const int wid1 = wordid[mrow0 + 64 + lrow];
  const bf16* srcA0 = embp + (size_t)wid0*320 + qsw;
  const bf16* srcA1 = embp + (size_t)wid1*320 + qsw;
  const bf16* srcB0 = Wpad + (size_t)(0*512 + nblk + lrow)*320 + qsw;
  const bf16* srcB1 = Wpad + (size_t)(1*512 + nblk + lrow)*320 + qsw;
  const bf16* srcB2 = Wpad + (size_t)(2*512 + nblk + lrow)*320 + qsw;

  const int sA   = (t>>1)&3;
  const int aoff = lane16*32 + ((quad ^ sA)*8);          // + rt*512
  const int boff = (w*16 + lane16)*32 + ((quad ^ sA)*8); // + g*2048

  f32x4 acc[3][8];
  const f32x4 zero = {0.f,0.f,0.f,0.f};
  #pragma unroll
  for(int o=0;o<3;o++){
    #pragma unroll
    for(int rt=0;rt<8;rt++) acc[o][rt]=zero;
  }

  // prologue: tiles 0 and 1 in flight; wait tile 0 (oldest 5), keep tile 1 flying
  {
    gload16(srcA0     , lsA[0] + wb);        gload16(srcA1     , lsA[0] + 2048 + wb);
    gload16(srcB0     , lsB[0] + wb);        gload16(srcB1     , lsB[0] + 2048 + wb);
    gload16(srcB2     , lsB[0] + 4096 + wb);
    gload16(srcA0 + 32, lsA[1] + wb);        gload16(srcA1 + 32, lsA[1] + 2048 + wb);
    gload16(srcB0 + 32, lsB[1] + wb);        gload16(srcB1 + 32, lsB[1] + 2048 + wb);
    gload16(srcB2 + 32, lsB[1] + 4096 + wb);
  }
  FENCE_VM(5);

  for (int ks = 0; ks < 10; ks++){
    const int cur = ks & 1;
    bf16x8 bfrag[3], afrag[8];
    #pragma unroll
    for(int g=0;g<3;g++) bfrag[g] = *(const bf16x8*)&lsB[cur][g*2048 + boff];
    #pragma unroll
    for(int rt=0;rt<8;rt++) afrag[rt] = *(const bf16x8*)&lsA[cur][rt*512 + aoff];
    FENCE_LGKM;                               // frags in regs; buf[cur] free
    if (ks < 8){
      const int k0 = (ks+2)*32;
      gload16(srcA0 + k0, lsA[cur] + wb);        gload16(srcA1 + k0, lsA[cur] + 2048 + wb);
      gload16(srcB0 + k0, lsB[cur] + wb);        gload16(srcB1 + k0, lsB[cur] + 2048 + wb);
      gload16(srcB2 + k0, lsB[cur] + 4096 + wb);
    }
    __builtin_amdgcn_s_setprio(1);
    #pragma unroll
    for(int rt=0;rt<8;rt++){
      #pragma unroll
      for(int g=0;g<3;g++)
        acc[g][rt] = __builtin_amdgcn_mfma_f32_16x16x32_bf16(afrag[rt], bfrag[g], acc[g][rt], 0,0,0);
    }
    __builtin_amdgcn_s_setprio(0);
    if (ks < 8)      FENCE_VM(5);             // tile ks+1 done; ks+2 stays in flight
    else if (ks < 9) FENCE_VM(0);             // tail: drain last tile
  }
  const int j = nblk + w*16 + lane16;
  const float bi=Wb[j], bo=Wb[512+j], bu=Wb[1024+j];
  #pragma unroll
  for(int rt=0;rt<8;rt++){
    #pragma unroll
    for(int reg=0;reg<4;reg++){
      const int row = mrow0 + rt*16 + quad*4 + reg;   // C/D: row=quad*4+reg, col=lane16
      float iv=acc[0][rt][reg]+bi, ov=acc[1][rt][reg]+bo, uv=acc[2][rt][reg]+bu;
      float c = sigm(iv)*tanh_f(uv);
      float h = sigm(ov)*tanh_f(c);
      ccur[(size_t)row*512 + j] = c;
      hcur[(size_t)row*512 + j] = (bf16)h;
    }
  }
}

// ---- level BM=64: R20 schedule at 48KB LDS, 3 blocks/CU (R23, proven) ----
__global__ __launch_bounds__(256, 3)
void level_kernel(const bf16* __restrict__ hprev, bf16* __restrict__ hcur,
                  const float* __restrict__ cprev, float* __restrict__ ccur,
                  const bf16* __restrict__ Uall, const float* __restrict__ Uioub,
                  const float* __restrict__ Ufb)
{
  __shared__ bf16 lsA[2][64*32];
  __shared__ bf16 lsB[2][320*32];
  const int t = threadIdx.x;
  const int mrow0 = blockIdx.x*64, nblk = blockIdx.y*64;
  const int lane16 = t&15, quad = (t&63)>>4, w = t>>6;

  const int lrow = t>>2;                                 // 0..63
  const int qsw  = ((t&3) ^ ((t>>3)&3))*8;               // swizzled src k-chunk (elems)
  const int wb   = (t & 192)*8;                          // wave-uniform LDS dest base

  const bf16* srcA0 = hprev + (size_t)(mrow0 + lrow)*1024 + qsw;
  const bf16* srcB0 = Uall + (size_t)(0*512 + nblk + lrow)*1024 + qsw;
  const bf16* srcB1 = Uall + (size_t)(1*512 + nblk + lrow)*1024 + qsw;
  const bf16* srcB2 = Uall + (size_t)(2*512 + nblk + lrow)*1024 + qsw;
  const bf16* srcB3 = Uall + (size_t)(3*512 + nblk + lrow)*1024 + qsw;
  const bf16* srcB4 = Uall + (size_t)(4*512 + nblk + lrow)*1024 + qsw;

  const int sA   = (t>>1)&3;
  const int aoff = lane16*32 + ((quad ^ sA)*8);          // + rt*512
  const int boff = (w*16 + lane16)*32 + ((quad ^ sA)*8); // + g*2048

#define LV64_DMA(buf, k0) do{ \
  gload16(srcA0 + (k0), lsA[buf] + wb); \
  gload16(srcB0 + (k0), lsB[buf] + wb);        gload16(srcB1 + (k0), lsB[buf] + 2048 + wb); \
  gload16(srcB2 + (k0), lsB[buf] + 4096 + wb); gload16(srcB3 + (k0), lsB[buf] + 6144 + wb); \
  gload16(srcB4 + (k0), lsB[buf] + 8192 + wb); }while(0)

  f32x4 acc[5][4];
  const f32x4 zero = {0.f,0.f,0.f,0.f};
  #pragma unroll
  for(int o=0;o<5;o++){
    #pragma unroll
    for(int rt=0;rt<4;rt++) acc[o][rt]=zero;
  }

  // prologue: tiles 0 and 1 in flight; wait tile 0 (oldest 6), keep tile 1 flying
  LV64_DMA(0, 0); LV64_DMA(1, 32);
  FENCE_VM(6);

  for (int ks = 0; ks < 32; ks++){
    const int cur = ks & 1;
    bf16x8 bfrag[5], afrag[4];
    #pragma unroll
    for(int g=0;g<5;g++) bfrag[g] = *(const bf16x8*)&lsB[cur][g*2048 + boff];
    #pragma unroll
    for(int rt=0;rt<4;rt++) afrag[rt] = *(const bf16x8*)&lsA[cur][rt*512 + aoff];
    FENCE_LGKM;                               // frags in regs; buf[cur] free
    if (ks < 30){
      LV64_DMA(cur, (ks+2)*32);
    }
    __builtin_amdgcn_s_setprio(1);
    #pragma unroll
    for(int rt=0;rt<4;rt++){
      #pragma unroll
      for(int g=0;g<5;g++)
        acc[g][rt] = __builtin_amdgcn_mfma_f32_16x16x32_bf16(afrag[rt], bfrag[g], acc[g][rt], 0,0,0);
    }
    __builtin_amdgcn_s_setprio(0);
    if (ks < 30)       FENCE_VM(6);           // tile ks+1 done; ks+2 stays in flight
    else if (ks < 31)  FENCE_VM(0);           // tail: drain last tile
  }

  const int j = nblk + w*16 + lane16;
  const float bi =Uioub[j], bo=Uioub[512+j], bu=Uioub[1024+j];
  const float bfl=Ufb[j],   bfr=Ufb[512+j];
  #pragma unroll
  for(int rt=0;rt<4;rt++){
    #pragma unroll
    for(int reg=0;reg<4;reg++){
      const int row = mrow0 + rt*16 + quad*4 + reg;
      float iv=acc[0][rt][reg]+bi, ov=acc[1][rt][reg]+bo, uv=acc[2][rt][reg]+bu;
      float fl=acc[3][rt][reg]+bfl, fr=acc[4][rt][reg]+bfr;
      float cl = cprev[((size_t)row*2  )*512 + j];
      float cr = cprev[((size_t)row*2+1)*512 + j];
      float cf = sigm(fl)*cl + sigm(fr)*cr;
      float c  = sigm(iv)*tanh_f(uv) + cf;
      float h  = sigm(ov)*tanh_f(c);
      ccur[(size_t)row*512 + j] = c;
      hcur[(size_t)row*512 + j] = (bf16)h;
    }
  }
#undef LV64_DMA
}

// ---- level BM=128 (R25, proven; kept as fallback, unused this round) ----
__global__ __launch_bounds__(256, 2)
void level128_kernel(const bf16* __restrict__ hprev, bf16* __restrict__ hcur,
                     const float* __restrict__ cprev, float* __restrict__ ccur,
                     const bf16* __restrict__ Uall, const float* __restrict__ Uioub,
                     const float* __restrict__ Ufb)
{
  __shared__ bf16 lsA[128*32];                           // SINGLE buffer
  __shared__ bf16 lsB[2][320*32];
  const int t = threadIdx.x;
  const int mrow0 = blockIdx.x*128, nblk = blockIdx.y*64;
  const int lane16 = t&15, quad = (t&63)>>4, w = t>>6;

  const int lrow = t>>2;                                 // 0..63
  const int qsw  = ((t&3) ^ ((t>>3)&3))*8;               // swizzled src k-chunk (elems)
  const int wb   = (t & 192)*8;                          // wave-uniform LDS dest base

  const bf16* srcA0 = hprev + (size_t)(mrow0 + lrow)*1024 + qsw;
  const bf16* srcA1 = hprev + (size_t)(mrow0 + 64 + lrow)*1024 + qsw;
  const bf16* srcB0 = Uall + (size_t)(0*512 + nblk + lrow)*1024 + qsw;
  const bf16* srcB1 = Uall + (size_t)(1*512 + nblk + lrow)*1024 + qsw;
  const bf16* srcB2 = Uall + (size_t)(2*512 + nblk + lrow)*1024 + qsw;
  const bf16* srcB3 = Uall + (size_t)(3*512 + nblk + lrow)*1024 + qsw;
  const bf16* srcB4 = Uall + (size_t)(4*512 + nblk + lrow)*1024 + qsw;

  const int sA   = (t>>1)&3;
  const int aoff = lane16*32 + ((quad ^ sA)*8);          // + rt*512
  const int boff = (w*16 + lane16)*32 + ((quad ^ sA)*8); // + g*2048

#define LVL_DMA_A(k0) do{ \
  gload16(srcA0 + (k0), lsA + wb);             gload16(srcA1 + (k0), lsA + 2048 + wb); }while(0)
#define LVL_DMA_B(buf, k0) do{ \
  gload16(srcB0 + (k0), lsB[buf] + wb);        gload16(srcB1 + (k0), lsB[buf] + 2048 + wb); \
  gload16(srcB2 + (k0), lsB[buf] + 4096 + wb); gload16(srcB3 + (k0), lsB[buf] + 6144 + wb); \
  gload16(srcB4 + (k0), lsB[buf] + 8192 + wb); }while(0)

  f32x4 acc[5][8];
  const f32x4 zero = {0.f,0.f,0.f,0.f};
  #pragma unroll
  for(int o=0;o<5;o++){
    #pragma unroll
    for(int rt=0;rt<8;rt++) acc[o][rt]=zero;
  }

  LVL_DMA_A(0); LVL_DMA_B(0, 0);
  LVL_DMA_B(1, 32);
  FENCE_VM(5);

  for (int ks = 0; ks < 32; ks++){
    const int cur = ks & 1;
    bf16x8 bfrag[5], afrag[8];
    #pragma unroll
    for(int g=0;g<5;g++) bfrag[g] = *(const bf16x8*)&lsB[cur][g*2048 + boff];
    #pragma unroll
    for(int rt=0;rt<8;rt++) afrag[rt] = *(const bf16x8*)&lsA[rt*512 + aoff];
    FENCE_LGKM;
    if (ks < 31) LVL_DMA_A(ks*32 + 32);
    if (ks < 30) LVL_DMA_B(cur, (ks+2)*32);
    __builtin_amdgcn_s_setprio(1);
    #pragma unroll
    for(int rt=0;rt<8;rt++){
      #pragma unroll
      for(int g=0;g<5;g++)
        acc[g][rt] = __builtin_amdgcn_mfma_f32_16x16x32_bf16(afrag[rt], bfrag[g], acc[g][rt], 0,0,0);
    }
    __builtin_amdgcn_s_setprio(0);
    if (ks < 30)       FENCE_VM(5);
    else if (ks < 31)  FENCE_VM(0);
  }

  const int j = nblk + w*16 + lane16;
  const float bi =Uioub[j], bo=Uioub[512+j], bu=Uioub[1024+j];
  const float bfl=Ufb[j],   bfr=Ufb[512+j];
  #pragma unroll
  for(int rt=0;rt<8;rt++){
    #pragma unroll
    for(int reg=0;reg<4;reg++){
      const int row = mrow0 + rt*16 + quad*4 + reg;
      float iv=acc[0][rt][reg]+bi, ov=acc[1][rt][reg]+bo, uv=acc[2][rt][reg]+bu;
      float fl=acc[3][rt][reg]+bfl, fr=acc[4][rt][reg]+bfr;
      float cl = cprev[((size_t)row*2  )*512 + j];
      float cr = cprev[((size_t)row*2+1)*512 + j];
      float cf = sigm(fl)*cl + sigm(fr)*cr;
      float c  = sigm(iv)*tanh_f(uv) + cf;
      float h  = sigm(ov)*tanh_f(c);
      ccur[(size_t)row*512 + j] = c;
      hcur[(size_t)row*512 + j] = (bf16)h;
    }
  }
#undef LVL_DMA_A
#undef LVL_DMA_B
}

// ---- logits (verbatim GEMV, proven): single-level version for leaf chunks ----
__global__ __launch_bounds__(256)
void logits_kernel(const bf16* __restrict__ h, const float* __restrict__ linw,
                   const float* __restrict__ linb, float* __restrict__ out,
                   int rowbase, int lgm, int mask, int off){
  const int row = blockIdx.x*4 + (threadIdx.x>>6);
  const int l = threadIdx.x & 63;
  bf16x8 hv = *(const bf16x8*)(h + (size_t)row*512 + l*8);
  float hf[8];
  #pragma unroll
  for(int jj=0;jj<8;jj++) hf[jj] = (float)hv[jj];
  float s[5];
  #pragma unroll
  for(int c=0;c<5;c++){
    const f32x4 w0 = *(const f32x4*)(linw + c*512 + l*8);
    const f32x4 w1 = *(const f32x4*)(linw + c*512 + l*8 + 4);
    float a = 0.f;
    #pragma unroll
    for(int jj=0;jj<4;jj++) a += hf[jj]*w0[jj] + hf[4+jj]*w1[jj];
    s[c]=a;
  }
  #pragma unroll
  for(int o=32;o>0;o>>=1){
    #pragma unroll
    for(int c=0;c<5;c++) s[c] += __shfl_down(s[c], o, 64);
  }
  if (l==0){
    const int g = rowbase + row;
    const int node = (g>>lgm)*511 + off + (g&mask);
    #pragma unroll
    for(int c=0;c<5;c++) out[(size_t)node*5+c] = s[c] + linb[c];
  }
}

// ---- logits2: two levels in one dispatch (same GEMV; per-row source select) ----
__global__ __launch_bounds__(256)
void logits2_kernel(const bf16* __restrict__ ha, int rows_a, int lgm_a, int mask_a, int off_a,
                    const bf16* __restrict__ hb, int lgm_b, int mask_b, int off_b,
                    const float* __restrict__ linw, const float* __restrict__ linb,
                    float* __restrict__ out){
  const int row = blockIdx.x*4 + (threadIdx.x>>6);
  const int l = threadIdx.x & 63;
  const bf16* hrow; int g, lgm, mask, off;
  if (row < rows_a){ hrow = ha + (size_t)row*512;            g = row;           lgm=lgm_a; mask=mask_a; off=off_a; }
  else             { hrow = hb + (size_t)(row-rows_a)*512;   g = row - rows_a;  lgm=lgm_b; mask=mask_b; off=off_b; }
  bf16x8 hv = *(const bf16x8*)(hrow + l*8);
  float hf[8];
  #pragma unroll
  for(int jj=0;jj<8;jj++) hf[jj] = (float)hv[jj];
  float s[5];
  #pragma unroll
  for(int c=0;c<5;c++){
    const f32x4 w0 = *(const f32x4*)(linw + c*512 + l*8);
    const f32x4 w1 = *(const f32x4*)(linw + c*512 + l*8 + 4);
    float a = 0.f;
    #pragma unroll
    for(int jj=0;jj<4;jj++) a += hf[jj]*w0[jj] + hf[4+jj]*w1[jj];
    s[c]=a;
  }
  #pragma unroll
  for(int o=32;o>0;o>>=1){
    #pragma unroll
    for(int c=0;c<5;c++) s[c] += __shfl_down(s[c], o, 64);
  }
  if (l==0){
    const int node = (g>>lgm)*511 + off + (g&mask);
    #pragma unroll
    for(int c=0;c<5;c++) out[(size_t)node*5+c] = s[c] + linb[c];
  }
}

__global__ void zero_out(float* out, int n){
  int i = blockIdx.x*256 + threadIdx.x;
  if (i < n) out[i] = 0.f;
}

extern "C" void kernel_launch(void* const* d_in, const int* in_sizes, int n_in,
                              void* d_out, int out_size, void* d_ws, size_t ws_size,
                              hipStream_t stream)
{
  const int*   wordid = (const int*)d_in[0];
  const float* emb    = (const float*)d_in[1];
  const float* Wiou   = (const float*)d_in[2];
  const float* Wioub  = (const float*)d_in[3];
  const float* Uiou   = (const float*)d_in[4];
  const float* Uioub  = (const float*)d_in[5];
  const float* Uf     = (const float*)d_in[6];
  const float* Ufb    = (const float*)d_in[7];
  const float* linw   = (const float*)d_in[8];
  const float* linb   = (const float*)d_in[9];
  float* out = (float*)d_out;

  // ---- fixed-region layout (R7/R14) ----
  const size_t oWPD  = 0;
  const size_t oUALL = oWPD  + (size_t)1536*320*2;
  const size_t oEMB  = oUALL + (size_t)2560*1024*2;
  const size_t oH1   = oEMB  + (size_t)32000*320*2;
  const size_t oC1   = oH1   + (size_t)32768*512*2;
  const size_t oH0   = oC1   + (size_t)32768*512*4;
  size_t R0 = 0;
  {
    const size_t t2 = oH0 + (size_t)32768*512*(2+4);   // 228.0 MB
    const size_t t4 = oH0 + (size_t)16384*512*(2+4);   // 177.7 MB
    const size_t t8 = oH0 + (size_t) 8192*512*(2+4);   // 152.5 MB
    if      (ws_size >= t2) R0 = 32768;
    else if (ws_size >= t4) R0 = 16384;
    else if (ws_size >= t8) R0 = 8192;
  }
  if (R0 == 0){
    zero_out<<<(out_size+255)/256, 256, 0, stream>>>(out, out_size);
    return;
  }

  char* ws = (char*)d_ws;
  bf16*  Wpad = (bf16*)(ws + oWPD);
  bf16*  Uall = (bf16*)(ws + oUALL);
  bf16*  embp = (bf16*)(ws + oEMB);
  bf16*  h1   = (bf16*)(ws + oH1);
  float* c1   = (float*)(ws + oC1);
  bf16*  h0   = (bf16*)(ws + oH0);
  float* c0   = (float*)(ws + oH0 + R0*1024);

  cvt_all<<<41728, 320, 0, stream>>>(Wiou, Uiou, Uf, emb, Wpad, Uall, embp);

  const int offs[9] = {0,256,384,448,480,496,504,508,510};
  const int nchunk = (int)(65536 / R0);

  // ---- leaf + level-1, chunked through h0/c0 scratch (leaf logits per chunk) ----
  for (int ch = 0; ch < nchunk; ch++){
    const int* wid = wordid + (size_t)ch*R0;
    leaf128_kernel<<<dim3((int)(R0/128), 8), 256, 0, stream>>>(wid, embp, Wpad, Wioub,
                                                               h0, c0);
    logits_kernel<<<(int)(R0/4), 256, 0, stream>>>(h0, linw, linb, out,
                                                   (int)(ch*R0), 8, 255, 0);
    bf16*  h1c = h1 + (size_t)ch*(R0/2)*512;
    float* c1c = c1 + (size_t)ch*(R0/2)*512;
    const int orows = (int)(R0/2);
    level_kernel<<<dim3(orows/64, 8), 256, 0, stream>>>(h0, h1c, c0, c1c,
                                                        Uall, Uioub, Ufb);
  }

  // ---- levels 2..8 (ALL via BM=64 level_kernel this round); after each EVEN
  // level, one logits2 covers (lv-1, lv) ----
  for (int lv = 2; lv <= 8; lv++){
    const int rows = 65536 >> lv;
    const bf16*  hin  = (lv & 1) ? h0 : h1;
    bf16*        hout = (lv & 1) ? h1 : h0;
    const float* cin  = (lv & 1) ? c0 : c1;
    float*       cout = (lv & 1) ? c1 : c0;
    level_kernel<<<dim3(rows/64, 8), 256, 0, stream>>>(hin, hout, cin, cout,
                                                       Uall, Uioub, Ufb);
    if ((lv & 1) == 0){
      const int rows_a = 65536 >> (lv-1);        // lv-1 rows (in h1)
      const int rows_b = rows;                   // lv rows   (in h0)
      logits2_kernel<<<(rows_a + rows_b)/4, 256, 0, stream>>>(
          h1, rows_a, 8-(lv-1), (256>>(lv-1))-1, offs[lv-1],
          h0,         8-lv,     (256>>lv)-1,     offs[lv],
          linw, linb, out);
    }
  }
}

// Round 10
// 763.027 us; speedup vs baseline: 1.7673x; 1.1776x over previous
//
#include <hip/hip_runtime.h>
#include <hip/hip_bf16.h>

// TreeLSTM on MI355X. B=256 trees, 256 leaves (depth 9), H=512, C=5.
// f32 I/O; bf16 MFMA; f32 cell state. Output f32 [256,511,5].
//
// R28 = R25 (783.8us best) restored verbatim + vectorized cvt_all (float4
// loads, 4 elems/thread; alignment: row stride 1200B and the Uiou/Uf split
// are 16B-aligned, no vec4 straddle). R27 A/B answer: BM=64 on big levels =
// 138us vs 128's 108 (FETCH 145 vs 88 MB -- B-panel reuse halves; occupancy
// 29% didn't help) -> BM=128 routing restored. Structural map around R25 is
// complete: depth/null, drain0/-13%, coarser/spill, finer/null, occ-up/
// reuse-loss, tile-down/reuse-loss. 108us @ MfmaUtil 34% = sync-latency
// floor of the register-feasible schedule family.

typedef __bf16 bf16;
typedef bf16  bf16x8 __attribute__((ext_vector_type(8)));
typedef float f32x4  __attribute__((ext_vector_type(4)));

__device__ __forceinline__ float sigm(float x){ return 1.0f/(1.0f + __expf(-x)); }
__device__ __forceinline__ float tanh_f(float x){ return 1.0f - 2.0f/(__expf(2.0f*x)+1.0f); }

// async global->LDS, 16 bytes per lane. HW dest = wave-uniform base + lane*16.
__device__ __forceinline__ void gload16(const bf16* g, bf16* l){
  __builtin_amdgcn_global_load_lds(
      (const __attribute__((address_space(1))) void*)g,
      (__attribute__((address_space(3))) void*)l, 16, 0, 0);
}

// vmcnt(N) then barrier: own older DMAs landed; newest stay in flight.
#define FENCE_VM(N) do{ asm volatile("s_waitcnt vmcnt(" #N ")" ::: "memory"); \
  __builtin_amdgcn_sched_barrier(0); __builtin_amdgcn_s_barrier(); \
  __builtin_amdgcn_sched_barrier(0); }while(0)
// barrier that only certifies LDS reads landed in regs (no VMEM drain)
#define FENCE_LGKM do{ asm volatile("s_waitcnt lgkmcnt(0)" ::: "memory"); \
  __builtin_amdgcn_sched_barrier(0); __builtin_amdgcn_s_barrier(); \
  __builtin_amdgcn_sched_barrier(0); }while(0)

// ---- vectorized converts (R28): Wpad | embp | Uall, 4 f32 per thread ----
// vec4 regions: Wpad 1536*80, embp 32000*80, Uall 2560*1024/4.
__global__ void cvt_all(const float* __restrict__ Wiou, const float* __restrict__ Uiou,
                        const float* __restrict__ Uf, const float* __restrict__ emb,
                        bf16* __restrict__ Wpad, bf16* __restrict__ Uall,
                        bf16* __restrict__ embp){
  const long long gid = (long long)blockIdx.x*256 + threadIdx.x;  // vec4 index
  const long long NW = 122880, NE = 2560000, NU = 655360;
  if (gid < NW + NE){
    long long g = gid;
    const float* src; bf16* dst;
    if (g < NW){ src = Wiou; dst = Wpad; }
    else       { g -= NW; src = emb; dst = embp; }
    const int r = (int)(g / 80), v = (int)(g % 80);
    bf16 o0, o1, o2, o3;
    if (v < 75){   // cols 4v..4v+3 < 300; row base r*1200B is 16B-aligned
      const f32x4 x = *(const f32x4*)(src + (size_t)r*300 + v*4);
      o0=(bf16)x[0]; o1=(bf16)x[1]; o2=(bf16)x[2]; o3=(bf16)x[3];
    } else {       // cols 300..319: zero pad
      o0=o1=o2=o3=(bf16)0.f;
    }
    bf16* d = dst + (size_t)r*320 + v*4;
    d[0]=o0; d[1]=o1; d[2]=o2; d[3]=o3;
  } else {
    const long long i4 = gid - NW - NE;
    if (i4 < NU){
      const size_t i = (size_t)i4*4;   // both regions multiple of 4: no straddle
      const float* s = (i < (size_t)1536*1024) ? (Uiou + i)
                                               : (Uf + (i - (size_t)1536*1024));
      const f32x4 x = *(const f32x4*)s;
      bf16* d = Uall + i;
      d[0]=(bf16)x[0]; d[1]=(bf16)x[1]; d[2]=(bf16)x[2]; d[3]=(bf16)x[3];
    }
  }
}

// ---- leaf BM=128: gload_lds + counted-vmcnt depth-2 + setprio (R20, proven) ----
__global__ __launch_bounds__(256, 2)
void leaf128_kernel(const int* __restrict__ wordid, const bf16* __restrict__ embp,
                    const bf16* __restrict__ Wpad, const float* __restrict__ Wb,
                    bf16* __restrict__ hcur, float* __restrict__ ccur)
{
  __shared__ bf16 lsA[2][128*32];
  __shared__ bf16 lsB[2][192*32];
  const int t = threadIdx.x;
  const int mrow0 = blockIdx.x*128, nblk = blockIdx.y*64;
  const int lane16 = t&15, quad = (t&63)>>4, w = t>>6;

  const int lrow = t>>2;                                 // 0..63
  const int qsw  = ((t&3) ^ ((t>>3)&3))*8;               // swizzled src k-chunk (elems)
  const int wb   = (t & 192)*8;                          // wave-uniform LDS dest base

  const int wid0 = wordid[mrow0 + lrow];
  const int wid1 = wordid[mrow0 + 64 + lrow];
  const bf16* srcA0 = embp + (size_t)wid0*320 + qsw;
  const bf16* srcA1 = embp + (size_t)wid1*320 + qsw;
  const bf16* srcB0 = Wpad + (size_t)(0*512 + nblk + lrow)*320 + qsw;
  const bf16* srcB1 = Wpad + (size_t)(1*512 + nblk + lrow)*320 + qsw;
  const bf16* srcB2 = Wpad + (size_t)(2*512 + nblk + lrow)*320 + qsw;

  const int sA   = (t>>1)&3;
  const int aoff = lane16*32 + ((quad ^ sA)*8);          // + rt*512
  const int boff = (w*16 + lane16)*32 + ((quad ^ sA)*8); // + g*2048

  f32x4 acc[3][8];
  const f32x4 zero = {0.f,0.f,0.f,0.f};
  #pragma unroll
  for(int o=0;o<3;o++){
    #pragma unroll
    for(int rt=0;rt<8;rt++) acc[o][rt]=zero;
  }

  // prologue: tiles 0 and 1 in flight; wait tile 0 (oldest 5), keep tile 1 flying
  {
    gload16(srcA0     , lsA[0] + wb);        gload16(srcA1     , lsA[0] + 2048 + wb);
    gload16(srcB0     , lsB[0] + wb);        gload16(srcB1     , lsB[0] + 2048 + wb);
    gload16(srcB2     , lsB[0] + 4096 + wb);
    gload16(srcA0 + 32, lsA[1] + wb);        gload16(srcA1 + 32, lsA[1] + 2048 + wb);
    gload16(srcB0 + 32, lsB[1] + wb);        gload16(srcB1 + 32, lsB[1] + 2048 + wb);
    gload16(srcB2 + 32, lsB[1] + 4096 + wb);
  }
  FENCE_VM(5);

  for (int ks = 0; ks < 10; ks++){
    const int cur = ks & 1;
    bf16x8 bfrag[3], afrag[8];
    #pragma unroll
    for(int g=0;g<3;g++) bfrag[g] = *(const bf16x8*)&lsB[cur][g*2048 + boff];
    #pragma unroll
    for(int rt=0;rt<8;rt++) afrag[rt] = *(const bf16x8*)&lsA[cur][rt*512 + aoff];
    FENCE_LGKM;                               // frags in regs; buf[cur] free
    if (ks < 8){
      const int k0 = (ks+2)*32;
      gload16(srcA0 + k0, lsA[cur] + wb);        gload16(srcA1 + k0, lsA[cur] + 2048 + wb);
      gload16(srcB0 + k0, lsB[cur] + wb);        gload16(srcB1 + k0, lsB[cur] + 2048 + wb);
      gload16(srcB2 + k0, lsB[cur] + 4096 + wb);
    }
    __builtin_amdgcn_s_setprio(1);
    #pragma unroll
    for(int rt=0;rt<8;rt++){
      #pragma unroll
      for(int g=0;g<3;g++)
        acc[g][rt] = __builtin_amdgcn_mfma_f32_16x16x32_bf16(afrag[rt], bfrag[g], acc[g][rt], 0,0,0);
    }
    __builtin_amdgcn_s_setprio(0);
    if (ks < 8)      FENCE_VM(5);             // tile ks+1 done; ks+2 stays in flight
    else if (ks < 9) FENCE_VM(0);             // tail: drain last tile
  }
  const int j = nblk + w*16 + lane16;
  const float bi=Wb[j], bo=Wb[512+j], bu=Wb[1024+j];
  #pragma unroll
  for(int rt=0;rt<8;rt++){
    #pragma unroll
    for(int reg=0;reg<4;reg++){
      const int row = mrow0 + rt*16 + quad*4 + reg;   // C/D: row=quad*4+reg, col=lane16
      float iv=acc[0][rt][reg]+bi, ov=acc[1][rt][reg]+bo, uv=acc[2][rt][reg]+bu;
      float c = sigm(iv)*tanh_f(uv);
      float h = sigm(ov)*tanh_f(c);
      ccur[(size_t)row*512 + j] = c;
      hcur[(size_t)row*512 + j] = (bf16)h;
    }
  }
}

// ---- level BM=64: R20 schedule at 48KB LDS, 3 blocks/CU (R23, proven) ----
__global__ __launch_bounds__(256, 3)
void level_kernel(const bf16* __restrict__ hprev, bf16* __restrict__ hcur,
                  const float* __restrict__ cprev, float* __restrict__ ccur,
                  const bf16* __restrict__ Uall, const float* __restrict__ Uioub,
                  const float* __restrict__ Ufb)
{
  __shared__ bf16 lsA[2][64*32];
  __shared__ bf16 lsB[2][320*32];
  const int t = threadIdx.x;
  const int mrow0 = blockIdx.x*64, nblk = blockIdx.y*64;
  const int lane16 = t&15, quad = (t&63)>>4, w = t>>6;

  const int lrow = t>>2;                                 // 0..63
  const int qsw  = ((t&3) ^ ((t>>3)&3))*8;               // swizzled src k-chunk (elems)
  const int wb   = (t & 192)*8;                          // wave-uniform LDS dest base

  const bf16* srcA0 = hprev + (size_t)(mrow0 + lrow)*1024 + qsw;
  const bf16* srcB0 = Uall + (size_t)(0*512 + nblk + lrow)*1024 + qsw;
  const bf16* srcB1 = Uall + (size_t)(1*512 + nblk + lrow)*1024 + qsw;
  const bf16* srcB2 = Uall + (size_t)(2*512 + nblk + lrow)*1024 + qsw;
  const bf16* srcB3 = Uall + (size_t)(3*512 + nblk + lrow)*1024 + qsw;
  const bf16* srcB4 = Uall + (size_t)(4*512 + nblk + lrow)*1024 + qsw;

  const int sA   = (t>>1)&3;
  const int aoff = lane16*32 + ((quad ^ sA)*8);          // + rt*512
  const int boff = (w*16 + lane16)*32 + ((quad ^ sA)*8); // + g*2048

#define LV64_DMA(buf, k0) do{ \
  gload16(srcA0 + (k0), lsA[buf] + wb); \
  gload16(srcB0 + (k0), lsB[buf] + wb);        gload16(srcB1 + (k0), lsB[buf] + 2048 + wb); \
  gload16(srcB2 + (k0), lsB[buf] + 4096 + wb); gload16(srcB3 + (k0), lsB[buf] + 6144 + wb); \
  gload16(srcB4 + (k0), lsB[buf] + 8192 + wb); }while(0)

  f32x4 acc[5][4];
  const f32x4 zero = {0.f,0.f,0.f,0.f};
  #pragma unroll
  for(int o=0;o<5;o++){
    #pragma unroll
    for(int rt=0;rt<4;rt++) acc[o][rt]=zero;
  }

  // prologue: tiles 0 and 1 in flight; wait tile 0 (oldest 6), keep tile 1 flying
  LV64_DMA(0, 0); LV64_DMA(1, 32);
  FENCE_VM(6);

  for (int ks = 0; ks < 32; ks++){
    const int cur = ks & 1;
    bf16x8 bfrag[5], afrag[4];
    #pragma unroll
    for(int g=0;g<5;g++) bfrag[g] = *(const bf16x8*)&lsB[cur][g*2048 + boff];
    #pragma unroll
    for(int rt=0;rt<4;rt++) afrag[rt] = *(const bf16x8*)&lsA[cur][rt*512 + aoff];
    FENCE_LGKM;                               // frags in regs; buf[cur] free
    if (ks < 30){
      LV64_DMA(cur, (ks+2)*32);
    }
    __builtin_amdgcn_s_setprio(1);
    #pragma unroll
    for(int rt=0;rt<4;rt++){
      #pragma unroll
      for(int g=0;g<5;g++)
        acc[g][rt] = __builtin_amdgcn_mfma_f32_16x16x32_bf16(afrag[rt], bfrag[g], acc[g][rt], 0,0,0);
    }
    __builtin_amdgcn_s_setprio(0);
    if (ks < 30)       FENCE_VM(6);           // tile ks+1 done; ks+2 stays in flight
    else if (ks < 31)  FENCE_VM(0);           // tail: drain last tile
  }

  const int j = nblk + w*16 + lane16;
  const float bi =Uioub[j], bo=Uioub[512+j], bu=Uioub[1024+j];
  const float bfl=Ufb[j],   bfr=Ufb[512+j];
  #pragma unroll
  for(int rt=0;rt<4;rt++){
    #pragma unroll
    for(int reg=0;reg<4;reg++){
      const int row = mrow0 + rt*16 + quad*4 + reg;
      float iv=acc[0][rt][reg]+bi, ov=acc[1][rt][reg]+bo, uv=acc[2][rt][reg]+bu;
      float fl=acc[3][rt][reg]+bfl, fr=acc[4][rt][reg]+bfr;
      float cl = cprev[((size_t)row*2  )*512 + j];
      float cr = cprev[((size_t)row*2+1)*512 + j];
      float cf = sigm(fl)*cl + sigm(fr)*cr;
      float c  = sigm(iv)*tanh_f(uv) + cf;
      float h  = sigm(ov)*tanh_f(c);
      ccur[(size_t)row*512 + j] = c;
      hcur[(size_t)row*512 + j] = (bf16)h;
    }
  }
#undef LV64_DMA
}

// ---- level BM=128: single-buffer A (48KB LDS) + counted vmcnt (R25, proven) ----
__global__ __launch_bounds__(256, 2)
void level128_kernel(const bf16* __restrict__ hprev, bf16* __restrict__ hcur,
                     const float* __restrict__ cprev, float* __restrict__ ccur,
                     const bf16* __restrict__ Uall, const float* __restrict__ Uioub,
                     const float* __restrict__ Ufb)
{
  __shared__ bf16 lsA[128*32];                           // SINGLE buffer
  __shared__ bf16 lsB[2][320*32];
  const int t = threadIdx.x;
  const int mrow0 = blockIdx.x*128, nblk = blockIdx.y*64;
  const int lane16 = t&15, quad = (t&63)>>4, w = t>>6;

  const int lrow = t>>2;                                 // 0..63
  const int qsw  = ((t&3) ^ ((t>>3)&3))*8;               // swizzled src k-chunk (elems)
  const int wb   = (t & 192)*8;                          // wave-uniform LDS dest base

  const bf16* srcA0 = hprev + (size_t)(mrow0 + lrow)*1024 + qsw;
  const bf16* srcA1 = hprev + (size_t)(mrow0 + 64 + lrow)*1024 + qsw;
  const bf16* srcB0 = Uall + (size_t)(0*512 + nblk + lrow)*1024 + qsw;
  const bf16* srcB1 = Uall + (size_t)(1*512 + nblk + lrow)*1024 + qsw;
  const bf16* srcB2 = Uall + (size_t)(2*512 + nblk + lrow)*1024 + qsw;
  const bf16* srcB3 = Uall + (size_t)(3*512 + nblk + lrow)*1024 + qsw;
  const bf16* srcB4 = Uall + (size_t)(4*512 + nblk + lrow)*1024 + qsw;

  const int sA   = (t>>1)&3;
  const int aoff = lane16*32 + ((quad ^ sA)*8);          // + rt*512
  const int boff = (w*16 + lane16)*32 + ((quad ^ sA)*8); // + g*2048

// A refill: must be issued BEFORE B[ks+2] so it is OLDER -> steady FENCE_VM(5)
// waits it while keeping B[ks+2]'s 5 ops in flight.
#define LVL_DMA_A(k0) do{ \
  gload16(srcA0 + (k0), lsA + wb);             gload16(srcA1 + (k0), lsA + 2048 + wb); }while(0)
#define LVL_DMA_B(buf, k0) do{ \
  gload16(srcB0 + (k0), lsB[buf] + wb);        gload16(srcB1 + (k0), lsB[buf] + 2048 + wb); \
  gload16(srcB2 + (k0), lsB[buf] + 4096 + wb); gload16(srcB3 + (k0), lsB[buf] + 6144 + wb); \
  gload16(srcB4 + (k0), lsB[buf] + 8192 + wb); }while(0)

  f32x4 acc[5][8];
  const f32x4 zero = {0.f,0.f,0.f,0.f};
  #pragma unroll
  for(int o=0;o<5;o++){
    #pragma unroll
    for(int rt=0;rt<8;rt++) acc[o][rt]=zero;
  }

  // prologue: A0+B0 (oldest 7), B1 (5, stays in flight)
  LVL_DMA_A(0); LVL_DMA_B(0, 0);
  LVL_DMA_B(1, 32);
  FENCE_VM(5);                                 // waits A0(2)+B0(5); keeps B1 flying

  for (int ks = 0; ks < 32; ks++){
    const int cur = ks & 1;
    bf16x8 bfrag[5], afrag[8];
    #pragma unroll
    for(int g=0;g<5;g++) bfrag[g] = *(const bf16x8*)&lsB[cur][g*2048 + boff];
    #pragma unroll
    for(int rt=0;rt<8;rt++) afrag[rt] = *(const bf16x8*)&lsA[rt*512 + aoff];
    FENCE_LGKM;                               // all waves consumed lsA + lsB[cur]
    if (ks < 31) LVL_DMA_A(ks*32 + 32);       // refill single A (older than B below)
    if (ks < 30) LVL_DMA_B(cur, (ks+2)*32);   // refill B[cur] (newest 5, spans fence)
    __builtin_amdgcn_s_setprio(1);
    #pragma unroll
    for(int rt=0;rt<8;rt++){
      #pragma unroll
      for(int g=0;g<5;g++)
        acc[g][rt] = __builtin_amdgcn_mfma_f32_16x16x32_bf16(afrag[rt], bfrag[g], acc[g][rt], 0,0,0);
    }
    __builtin_amdgcn_s_setprio(0);
    if (ks < 30)       FENCE_VM(5);           // waits B[ks+1]+A[ks+1]; keeps B[ks+2]
    else if (ks < 31)  FENCE_VM(0);           // tail: drain B31 + A31
  }

  const int j = nblk + w*16 + lane16;
  const float bi =Uioub[j], bo=Uioub[512+j], bu=Uioub[1024+j];
  const float bfl=Ufb[j],   bfr=Ufb[512+j];
  #pragma unroll
  for(int rt=0;rt<8;rt++){
    #pragma unroll
    for(int reg=0;reg<4;reg++){
      const int row = mrow0 + rt*16 + quad*4 + reg;
      float iv=acc[0][rt][reg]+bi, ov=acc[1][rt][reg]+bo, uv=acc[2][rt][reg]+bu;
      float fl=acc[3][rt][reg]+bfl, fr=acc[4][rt][reg]+bfr;
      float cl = cprev[((size_t)row*2  )*512 + j];
      float cr = cprev[((size_t)row*2+1)*512 + j];
      float cf = sigm(fl)*cl + sigm(fr)*cr;
      float c  = sigm(iv)*tanh_f(uv) + cf;
      float h  = sigm(ov)*tanh_f(c);
      ccur[(size_t)row*512 + j] = c;
      hcur[(size_t)row*512 + j] = (bf16)h;
    }
  }
#undef LVL_DMA_A
#undef LVL_DMA_B
}

// ---- logits (verbatim GEMV, proven): single-level version for leaf chunks ----
__global__ __launch_bounds__(256)
void logits_kernel(const bf16* __restrict__ h, const float* __restrict__ linw,
                   const float* __restrict__ linb, float* __restrict__ out,
                   int rowbase, int lgm, int mask, int off){
  const int row = blockIdx.x*4 + (threadIdx.x>>6);
  const int l = threadIdx.x & 63;
  bf16x8 hv = *(const bf16x8*)(h + (size_t)row*512 + l*8);
  float hf[8];
  #pragma unroll
  for(int jj=0;jj<8;jj++) hf[jj] = (float)hv[jj];
  float s[5];
  #pragma unroll
  for(int c=0;c<5;c++){
    const f32x4 w0 = *(const f32x4*)(linw + c*512 + l*8);
    const f32x4 w1 = *(const f32x4*)(linw + c*512 + l*8 + 4);
    float a = 0.f;
    #pragma unroll
    for(int jj=0;jj<4;jj++) a += hf[jj]*w0[jj] + hf[4+jj]*w1[jj];
    s[c]=a;
  }
  #pragma unroll
  for(int o=32;o>0;o>>=1){
    #pragma unroll
    for(int c=0;c<5;c++) s[c] += __shfl_down(s[c], o, 64);
  }
  if (l==0){
    const int g = rowbase + row;
    const int node = (g>>lgm)*511 + off + (g&mask);
    #pragma unroll
    for(int c=0;c<5;c++) out[(size_t)node*5+c] = s[c] + linb[c];
  }
}

// ---- logits2: two levels in one dispatch (same GEMV; per-row source select) ----
__global__ __launch_bounds__(256)
void logits2_kernel(const bf16* __restrict__ ha, int rows_a, int lgm_a, int mask_a, int off_a,
                    const bf16* __restrict__ hb, int lgm_b, int mask_b, int off_b,
                    const float* __restrict__ linw, const float* __restrict__ linb,
                    float* __restrict__ out){
  const int row = blockIdx.x*4 + (threadIdx.x>>6);
  const int l = threadIdx.x & 63;
  const bf16* hrow; int g, lgm, mask, off;
  if (row < rows_a){ hrow = ha + (size_t)row*512;            g = row;           lgm=lgm_a; mask=mask_a; off=off_a; }
  else             { hrow = hb + (size_t)(row-rows_a)*512;   g = row - rows_a;  lgm=lgm_b; mask=mask_b; off=off_b; }
  bf16x8 hv = *(const bf16x8*)(hrow + l*8);
  float hf[8];
  #pragma unroll
  for(int jj=0;jj<8;jj++) hf[jj] = (float)hv[jj];
  float s[5];
  #pragma unroll
  for(int c=0;c<5;c++){
    const f32x4 w0 = *(const f32x4*)(linw + c*512 + l*8);
    const f32x4 w1 = *(const f32x4*)(linw + c*512 + l*8 + 4);
    float a = 0.f;
    #pragma unroll
    for(int jj=0;jj<4;jj++) a += hf[jj]*w0[jj] + hf[4+jj]*w1[jj];
    s[c]=a;
  }
  #pragma unroll
  for(int o=32;o>0;o>>=1){
    #pragma unroll
    for(int c=0;c<5;c++) s[c] += __shfl_down(s[c], o, 64);
  }
  if (l==0){
    const int node = (g>>lgm)*511 + off + (g&mask);
    #pragma unroll
    for(int c=0;c<5;c++) out[(size_t)node*5+c] = s[c] + linb[c];
  }
}

__global__ void zero_out(float* out, int n){
  int i = blockIdx.x*256 + threadIdx.x;
  if (i < n) out[i] = 0.f;
}

extern "C" void kernel_launch(void* const* d_in, const int* in_sizes, int n_in,
                              void* d_out, int out_size, void* d_ws, size_t ws_size,
                              hipStream_t stream)
{
  const int*   wordid = (const int*)d_in[0];
  const float* emb    = (const float*)d_in[1];
  const float* Wiou   = (const float*)d_in[2];
  const float* Wioub  = (const float*)d_in[3];
  const float* Uiou   = (const float*)d_in[4];
  const float* Uioub  = (const float*)d_in[5];
  const float* Uf     = (const float*)d_in[6];
  const float* Ufb    = (const float*)d_in[7];
  const float* linw   = (const float*)d_in[8];
  const float* linb   = (const float*)d_in[9];
  float* out = (float*)d_out;

  // ---- fixed-region layout (R7/R14) ----
  const size_t oWPD  = 0;
  const size_t oUALL = oWPD  + (size_t)1536*320*2;
  const size_t oEMB  = oUALL + (size_t)2560*1024*2;
  const size_t oH1   = oEMB  + (size_t)32000*320*2;
  const size_t oC1   = oH1   + (size_t)32768*512*2;
  const size_t oH0   = oC1   + (size_t)32768*512*4;
  size_t R0 = 0;
  {
    const size_t t2 = oH0 + (size_t)32768*512*(2+4);   // 228.0 MB
    const size_t t4 = oH0 + (size_t)16384*512*(2+4);   // 177.7 MB
    const size_t t8 = oH0 + (size_t) 8192*512*(2+4);   // 152.5 MB
    if      (ws_size >= t2) R0 = 32768;
    else if (ws_size >= t4) R0 = 16384;
    else if (ws_size >= t8) R0 = 8192;
  }
  if (R0 == 0){
    zero_out<<<(out_size+255)/256, 256, 0, stream>>>(out, out_size);
    return;
  }

  char* ws = (char*)d_ws;
  bf16*  Wpad = (bf16*)(ws + oWPD);
  bf16*  Uall = (bf16*)(ws + oUALL);
  bf16*  embp = (bf16*)(ws + oEMB);
  bf16*  h1   = (bf16*)(ws + oH1);
  float* c1   = (float*)(ws + oC1);
  bf16*  h0   = (bf16*)(ws + oH0);
  float* c0   = (float*)(ws + oH0 + R0*1024);

  // 122880 + 2560000 + 655360 = 3,338,240 vec4 tasks = 13040 blocks * 256
  cvt_all<<<13040, 256, 0, stream>>>(Wiou, Uiou, Uf, emb, Wpad, Uall, embp);

  const int offs[9] = {0,256,384,448,480,496,504,508,510};
  const int nchunk = (int)(65536 / R0);

  // ---- leaf + level-1, chunked through h0/c0 scratch (leaf logits per chunk) ----
  for (int ch = 0; ch < nchunk; ch++){
    const int* wid = wordid + (size_t)ch*R0;
    leaf128_kernel<<<dim3((int)(R0/128), 8), 256, 0, stream>>>(wid, embp, Wpad, Wioub,
                                                               h0, c0);
    logits_kernel<<<(int)(R0/4), 256, 0, stream>>>(h0, linw, linb, out,
                                                   (int)(ch*R0), 8, 255, 0);
    bf16*  h1c = h1 + (size_t)ch*(R0/2)*512;
    float* c1c = c1 + (size_t)ch*(R0/2)*512;
    const int orows = (int)(R0/2);
    level128_kernel<<<dim3(orows/128, 8), 256, 0, stream>>>(h0, h1c, c0, c1c,
                                                            Uall, Uioub, Ufb);
  }

  // ---- levels 2..8; after each EVEN level, one logits2 covers (lv-1, lv) ----
  // Validity: lv-1's h (h1) is intact until lv+1 writes h1; lv's h (h0) until lv+2.
  for (int lv = 2; lv <= 8; lv++){
    const int rows = 65536 >> lv;
    const bf16*  hin  = (lv & 1) ? h0 : h1;
    bf16*        hout = (lv & 1) ? h1 : h0;
    const float* cin  = (lv & 1) ? c0 : c1;
    float*       cout = (lv & 1) ? c1 : c0;
    if (rows >= 8192)
      level128_kernel<<<dim3(rows/128, 8), 256, 0, stream>>>(hin, hout, cin, cout,
                                                             Uall, Uioub, Ufb);
    else
      level_kernel<<<dim3(rows/64, 8), 256, 0, stream>>>(hin, hout, cin, cout,
                                                         Uall, Uioub, Ufb);
    if ((lv & 1) == 0){
      const int rows_a = 65536 >> (lv-1);        // lv-1 rows (in h1)
      const int rows_b = rows;                   // lv rows   (in h0)
      logits2_kernel<<<(rows_a + rows_b)/4, 256, 0, stream>>>(
          h1, rows_a, 8-(lv-1), (256>>(lv-1))-1, offs[lv-1],
          h0,         8-lv,     (256>>lv)-1,     offs[lv],
          linw, linb, out);
    }
  }
}

// Round 11
// 758.267 us; speedup vs baseline: 1.7784x; 1.0063x over previous
//
#include <hip/hip_runtime.h>
#include <hip/hip_bf16.h>

// TreeLSTM on MI355X. B=256 trees, 256 leaves (depth 9), H=512, C=5.
// f32 I/O; bf16 MFMA; f32 cell state. Output f32 [256,511,5].
//
// R29 = R28 (763us best) with big levels (rows>=8192) moved to level256:
// BM=256 via 512 threads / 8 waves. Same R25 fence semantics, same per-
// thread register state (acc[5][8] + 13 frags ~ 128 VGPR -- the geometry
// axis that doubles work/barrier WITHOUT the R26 spill). 2x MFMA per
// barrier-pair + 16 waves/CU (4/SIMD, VGPR-pool exact fit) vs 8.
// LDS: lsA 256x32 single-buf (16KB, 2 gloads x 128 rows); lsB dbuf 6-gate
// 24KB so B = exactly 3 full 512-thread gloads: gates (0,1),(2,3),(4,pad).
// Pad gload: waves 4-7 re-read gate4 (L2 hit) into a never-read slot ->
// per-wave vmcnt counts UNIFORM (5 ops/tile/wave). Steady FENCE_VM(3)
// (queue: B[ks+1]=3, A[ks+1]=2, B[ks+2]=3). 64KB LDS -> 2 blocks/CU.
// leaf128 / level_kernel / logits / cvt(R28 vec4) verbatim.

typedef __bf16 bf16;
typedef bf16  bf16x8 __attribute__((ext_vector_type(8)));
typedef float f32x4  __attribute__((ext_vector_type(4)));

__device__ __forceinline__ float sigm(float x){ return 1.0f/(1.0f + __expf(-x)); }
__device__ __forceinline__ float tanh_f(float x){ return 1.0f - 2.0f/(__expf(2.0f*x)+1.0f); }

// async global->LDS, 16 bytes per lane. HW dest = wave-uniform base + lane*16.
__device__ __forceinline__ void gload16(const bf16* g, bf16* l){
  __builtin_amdgcn_global_load_lds(
      (const __attribute__((address_space(1))) void*)g,
      (__attribute__((address_space(3))) void*)l, 16, 0, 0);
}

// vmcnt(N) then barrier: own older DMAs landed; newest stay in flight.
#define FENCE_VM(N) do{ asm volatile("s_waitcnt vmcnt(" #N ")" ::: "memory"); \
  __builtin_amdgcn_sched_barrier(0); __builtin_amdgcn_s_barrier(); \
  __builtin_amdgcn_sched_barrier(0); }while(0)
// barrier that only certifies LDS reads landed in regs (no VMEM drain)
#define FENCE_LGKM do{ asm volatile("s_waitcnt lgkmcnt(0)" ::: "memory"); \
  __builtin_amdgcn_sched_barrier(0); __builtin_amdgcn_s_barrier(); \
  __builtin_amdgcn_sched_barrier(0); }while(0)

// ---- vectorized converts (R28): Wpad | embp | Uall, 4 f32 per thread ----
__global__ void cvt_all(const float* __restrict__ Wiou, const float* __restrict__ Uiou,
                        const float* __restrict__ Uf, const float* __restrict__ emb,
                        bf16* __restrict__ Wpad, bf16* __restrict__ Uall,
                        bf16* __restrict__ embp){
  const long long gid = (long long)blockIdx.x*256 + threadIdx.x;  // vec4 index
  const long long NW = 122880, NE = 2560000, NU = 655360;
  if (gid < NW + NE){
    long long g = gid;
    const float* src; bf16* dst;
    if (g < NW){ src = Wiou; dst = Wpad; }
    else       { g -= NW; src = emb; dst = embp; }
    const int r = (int)(g / 80), v = (int)(g % 80);
    bf16 o0, o1, o2, o3;
    if (v < 75){   // cols 4v..4v+3 < 300; row base r*1200B is 16B-aligned
      const f32x4 x = *(const f32x4*)(src + (size_t)r*300 + v*4);
      o0=(bf16)x[0]; o1=(bf16)x[1]; o2=(bf16)x[2]; o3=(bf16)x[3];
    } else {       // cols 300..319: zero pad
      o0=o1=o2=o3=(bf16)0.f;
    }
    bf16* d = dst + (size_t)r*320 + v*4;
    d[0]=o0; d[1]=o1; d[2]=o2; d[3]=o3;
  } else {
    const long long i4 = gid - NW - NE;
    if (i4 < NU){
      const size_t i = (size_t)i4*4;   // both regions multiple of 4: no straddle
      const float* s = (i < (size_t)1536*1024) ? (Uiou + i)
                                               : (Uf + (i - (size_t)1536*1024));
      const f32x4 x = *(const f32x4*)s;
      bf16* d = Uall + i;
      d[0]=(bf16)x[0]; d[1]=(bf16)x[1]; d[2]=(bf16)x[2]; d[3]=(bf16)x[3];
    }
  }
}

// ---- leaf BM=128: gload_lds + counted-vmcnt depth-2 + setprio (R20, proven) ----
__global__ __launch_bounds__(256, 2)
void leaf128_kernel(const int* __restrict__ wordid, const bf16* __restrict__ embp,
                    const bf16* __restrict__ Wpad, const float* __restrict__ Wb,
                    bf16* __restrict__ hcur, float* __restrict__ ccur)
{
  __shared__ bf16 lsA[2][128*32];
  __shared__ bf16 lsB[2][192*32];
  const int t = threadIdx.x;
  const int mrow0 = blockIdx.x*128, nblk = blockIdx.y*64;
  const int lane16 = t&15, quad = (t&63)>>4, w = t>>6;

  const int lrow = t>>2;                                 // 0..63
  const int qsw  = ((t&3) ^ ((t>>3)&3))*8;               // swizzled src k-chunk (elems)
  const int wb   = (t & 192)*8;                          // wave-uniform LDS dest base

  const int wid0 = wordid[mrow0 + lrow];
  const int wid1 = wordid[mrow0 + 64 + lrow];
  const bf16* srcA0 = embp + (size_t)wid0*320 + qsw;
  const bf16* srcA1 = embp + (size_t)wid1*320 + qsw;
  const bf16* srcB0 = Wpad + (size_t)(0*512 + nblk + lrow)*320 + qsw;
  const bf16* srcB1 = Wpad + (size_t)(1*512 + nblk + lrow)*320 + qsw;
  const bf16* srcB2 = Wpad + (size_t)(2*512 + nblk + lrow)*320 + qsw;

  const int sA   = (t>>1)&3;
  const int aoff = lane16*32 + ((quad ^ sA)*8);          // + rt*512
  const int boff = (w*16 + lane16)*32 + ((quad ^ sA)*8); // + g*2048

  f32x4 acc[3][8];
  const f32x4 zero = {0.f,0.f,0.f,0.f};
  #pragma unroll
  for(int o=0;o<3;o++){
    #pragma unroll
    for(int rt=0;rt<8;rt++) acc[o][rt]=zero;
  }

  // prologue: tiles 0 and 1 in flight; wait tile 0 (oldest 5), keep tile 1 flying
  {
    gload16(srcA0     , lsA[0] + wb);        gload16(srcA1     , lsA[0] + 2048 + wb);
    gload16(srcB0     , lsB[0] + wb);        gload16(srcB1     , lsB[0] + 2048 + wb);
    gload16(srcB2     , lsB[0] + 4096 + wb);
    gload16(srcA0 + 32, lsA[1] + wb);        gload16(srcA1 + 32, lsA[1] + 2048 + wb);
    gload16(srcB0 + 32, lsB[1] + wb);        gload16(srcB1 + 32, lsB[1] + 2048 + wb);
    gload16(srcB2 + 32, lsB[1] + 4096 + wb);
  }
  FENCE_VM(5);

  for (int ks = 0; ks < 10; ks++){
    const int cur = ks & 1;
    bf16x8 bfrag[3], afrag[8];
    #pragma unroll
    for(int g=0;g<3;g++) bfrag[g] = *(const bf16x8*)&lsB[cur][g*2048 + boff];
    #pragma unroll
    for(int rt=0;rt<8;rt++) afrag[rt] = *(const bf16x8*)&lsA[cur][rt*512 + aoff];
    FENCE_LGKM;                               // frags in regs; buf[cur] free
    if (ks < 8){
      const int k0 = (ks+2)*32;
      gload16(srcA0 + k0, lsA[cur] + wb);        gload16(srcA1 + k0, lsA[cur] + 2048 + wb);
      gload16(srcB0 + k0, lsB[cur] + wb);        gload16(srcB1 + k0, lsB[cur] + 2048 + wb);
      gload16(srcB2 + k0, lsB[cur] + 4096 + wb);
    }
    __builtin_amdgcn_s_setprio(1);
    #pragma unroll
    for(int rt=0;rt<8;rt++){
      #pragma unroll
      for(int g=0;g<3;g++)
        acc[g][rt] = __builtin_amdgcn_mfma_f32_16x16x32_bf16(afrag[rt], bfrag[g], acc[g][rt], 0,0,0);
    }
    __builtin_amdgcn_s_setprio(0);
    if (ks < 8)      FENCE_VM(5);             // tile ks+1 done; ks+2 stays in flight
    else if (ks < 9) FENCE_VM(0);             // tail: drain last tile
  }
  const int j = nblk + w*16 + lane16;
  const float bi=Wb[j], bo=Wb[512+j], bu=Wb[1024+j];
  #pragma unroll
  for(int rt=0;rt<8;rt++){
    #pragma unroll
    for(int reg=0;reg<4;reg++){
      const int row = mrow0 + rt*16 + quad*4 + reg;   // C/D: row=quad*4+reg, col=lane16
      float iv=acc[0][rt][reg]+bi, ov=acc[1][rt][reg]+bo, uv=acc[2][rt][reg]+bu;
      float c = sigm(iv)*tanh_f(uv);
      float h = sigm(ov)*tanh_f(c);
      ccur[(size_t)row*512 + j] = c;
      hcur[(size_t)row*512 + j] = (bf16)h;
    }
  }
}

// ---- level BM=64: R20 schedule at 48KB LDS, 3 blocks/CU (R23, proven) ----
__global__ __launch_bounds__(256, 3)
void level_kernel(const bf16* __restrict__ hprev, bf16* __restrict__ hcur,
                  const float* __restrict__ cprev, float* __restrict__ ccur,
                  const bf16* __restrict__ Uall, const float* __restrict__ Uioub,
                  const float* __restrict__ Ufb)
{
  __shared__ bf16 lsA[2][64*32];
  __shared__ bf16 lsB[2][320*32];
  const int t = threadIdx.x;
  const int mrow0 = blockIdx.x*64, nblk = blockIdx.y*64;
  const int lane16 = t&15, quad = (t&63)>>4, w = t>>6;

  const int lrow = t>>2;                                 // 0..63
  const int qsw  = ((t&3) ^ ((t>>3)&3))*8;               // swizzled src k-chunk (elems)
  const int wb   = (t & 192)*8;                          // wave-uniform LDS dest base

  const bf16* srcA0 = hprev + (size_t)(mrow0 + lrow)*1024 + qsw;
  const bf16* srcB0 = Uall + (size_t)(0*512 + nblk + lrow)*1024 + qsw;
  const bf16* srcB1 = Uall + (size_t)(1*512 + nblk + lrow)*1024 + qsw;
  const bf16* srcB2 = Uall + (size_t)(2*512 + nblk + lrow)*1024 + qsw;
  const bf16* srcB3 = Uall + (size_t)(3*512 + nblk + lrow)*1024 + qsw;
  const bf16* srcB4 = Uall + (size_t)(4*512 + nblk + lrow)*1024 + qsw;

  const int sA   = (t>>1)&3;
  const int aoff = lane16*32 + ((quad ^ sA)*8);          // + rt*512
  const int boff = (w*16 + lane16)*32 + ((quad ^ sA)*8); // + g*2048

#define LV64_DMA(buf, k0) do{ \
  gload16(srcA0 + (k0), lsA[buf] + wb); \
  gload16(srcB0 + (k0), lsB[buf] + wb);        gload16(srcB1 + (k0), lsB[buf] + 2048 + wb); \
  gload16(srcB2 + (k0), lsB[buf] + 4096 + wb); gload16(srcB3 + (k0), lsB[buf] + 6144 + wb); \
  gload16(srcB4 + (k0), lsB[buf] + 8192 + wb); }while(0)

  f32x4 acc[5][4];
  const f32x4 zero = {0.f,0.f,0.f,0.f};
  #pragma unroll
  for(int o=0;o<5;o++){
    #pragma unroll
    for(int rt=0;rt<4;rt++) acc[o][rt]=zero;
  }

  // prologue: tiles 0 and 1 in flight; wait tile 0 (oldest 6), keep tile 1 flying
  LV64_DMA(0, 0); LV64_DMA(1, 32);
  FENCE_VM(6);

  for (int ks = 0; ks < 32; ks++){
    const int cur = ks & 1;
    bf16x8 bfrag[5], afrag[4];
    #pragma unroll
    for(int g=0;g<5;g++) bfrag[g] = *(const bf16x8*)&lsB[cur][g*2048 + boff];
    #pragma unroll
    for(int rt=0;rt<4;rt++) afrag[rt] = *(const bf16x8*)&lsA[cur][rt*512 + aoff];
    FENCE_LGKM;                               // frags in regs; buf[cur] free
    if (ks < 30){
      LV64_DMA(cur, (ks+2)*32);
    }
    __builtin_amdgcn_s_setprio(1);
    #pragma unroll
    for(int rt=0;rt<4;rt++){
      #pragma unroll
      for(int g=0;g<5;g++)
        acc[g][rt] = __builtin_amdgcn_mfma_f32_16x16x32_bf16(afrag[rt], bfrag[g], acc[g][rt], 0,0,0);
    }
    __builtin_amdgcn_s_setprio(0);
    if (ks < 30)       FENCE_VM(6);           // tile ks+1 done; ks+2 stays in flight
    else if (ks < 31)  FENCE_VM(0);           // tail: drain last tile
  }

  const int j = nblk + w*16 + lane16;
  const float bi =Uioub[j], bo=Uioub[512+j], bu=Uioub[1024+j];
  const float bfl=Ufb[j],   bfr=Ufb[512+j];
  #pragma unroll
  for(int rt=0;rt<4;rt++){
    #pragma unroll
    for(int reg=0;reg<4;reg++){
      const int row = mrow0 + rt*16 + quad*4 + reg;
      float iv=acc[0][rt][reg]+bi, ov=acc[1][rt][reg]+bo, uv=acc[2][rt][reg]+bu;
      float fl=acc[3][rt][reg]+bfl, fr=acc[4][rt][reg]+bfr;
      float cl = cprev[((size_t)row*2  )*512 + j];
      float cr = cprev[((size_t)row*2+1)*512 + j];
      float cf = sigm(fl)*cl + sigm(fr)*cr;
      float c  = sigm(iv)*tanh_f(uv) + cf;
      float h  = sigm(ov)*tanh_f(c);
      ccur[(size_t)row*512 + j] = c;
      hcur[(size_t)row*512 + j] = (bf16)h;
    }
  }
#undef LV64_DMA
}

// ---- level BM=256 via 512 threads / 8 waves (R29): 2x work per barrier at
// constant per-thread registers; single-buf A; 6-gate B dbuf (gate5 = pad so
// per-wave vmcnt is uniform: 5 DMA ops/tile/wave) ----
__global__ __launch_bounds__(512, 1)
void level256_kernel(const bf16* __restrict__ hprev, bf16* __restrict__ hcur,
                     const float* __restrict__ cprev, float* __restrict__ ccur,
                     const bf16* __restrict__ Uall, const float* __restrict__ Uioub,
                     const float* __restrict__ Ufb)
{
  __shared__ bf16 lsA[256*32];                 // 16KB single buffer (rows 0..255)
  __shared__ bf16 lsB[2][6*2048];              // 2 x 24KB (gates 0..4 + pad)
  const int t = threadIdx.x;                   // 0..511
  const int mrow0 = blockIdx.x*256, nblk = blockIdx.y*64;
  const int lane16 = t&15, quad = (t&63)>>4;
  const int wc = (t>>6)&3;                     // column group (16 cols)
  const int wh = t>>8;                         // row half (0: rows 0-127, 1: 128-255)

  const int qsw  = ((t&3) ^ ((t>>3)&3))*8;     // swizzled src k-chunk (elems)
  const int wb   = (t & 448)*8;                // per-wave LDS dest base (elems)

  // A: 2 gloads x 128 rows (row = t>>2). Swizzle bits (row>>1)&3 = (t>>3)&3 ok
  // for both halves (+128 doesn't touch row bits 1-2).
  const int arow = t>>2;                       // 0..127
  const bf16* srcA_lo = hprev + (size_t)(mrow0 +       arow)*1024 + qsw;
  const bf16* srcA_hi = hprev + (size_t)(mrow0 + 128 + arow)*1024 + qsw;
  // B: 3 gloads; row = (t&255)>>2 (0..63), gate split by t>=256.
  const int brow  = (t&255)>>2;
  const int bhalf = t>>8;                      // 0 or 1
  const bf16* srcB01 = Uall + (size_t)((0+bhalf)*512 + nblk + brow)*1024 + qsw;
  const bf16* srcB23 = Uall + (size_t)((2+bhalf)*512 + nblk + brow)*1024 + qsw;
  const bf16* srcB4  = Uall + (size_t)(4*512         + nblk + brow)*1024 + qsw; // waves 4-7 dup -> pad slot

  const int sA   = (t>>1)&3;                   // = (lane16>>1)&3
  const int aoff = (wh*128 + lane16)*32 + ((quad ^ sA)*8);   // + rt*512
  const int boff = (wc*16 + lane16)*32 + ((quad ^ sA)*8);    // + g*2048

#define LV256_DMA_A(k0) do{ \
  gload16(srcA_lo + (k0), lsA + wb); \
  gload16(srcA_hi + (k0), lsA + 4096 + wb); }while(0)
#define LV256_DMA_B(buf, k0) do{ \
  gload16(srcB01 + (k0), lsB[buf] + wb); \
  gload16(srcB23 + (k0), lsB[buf] + 4096 + wb); \
  gload16(srcB4  + (k0), lsB[buf] + 8192 + wb); }while(0)

  f32x4 acc[5][8];
  const f32x4 zero = {0.f,0.f,0.f,0.f};
  #pragma unroll
  for(int o=0;o<5;o++){
    #pragma unroll
    for(int rt=0;rt<8;rt++) acc[o][rt]=zero;
  }

  // prologue: A0(2)+B0(3) oldest, B1(3) stays in flight
  LV256_DMA_A(0); LV256_DMA_B(0, 0);
  LV256_DMA_B(1, 32);
  FENCE_VM(3);                                 // waits A0+B0 (5 oldest); keeps B1

  for (int ks = 0; ks < 32; ks++){
    const int cur = ks & 1;
    bf16x8 bfrag[5], afrag[8];
    #pragma unroll
    for(int g=0;g<5;g++) bfrag[g] = *(const bf16x8*)&lsB[cur][g*2048 + boff];
    #pragma unroll
    for(int rt=0;rt<8;rt++) afrag[rt] = *(const bf16x8*)&lsA[rt*512 + aoff];
    FENCE_LGKM;                               // all waves consumed lsA + lsB[cur]
    if (ks < 31) LV256_DMA_A((ks+1)*32);      // refill single A (older than B below)
    if (ks < 30) LV256_DMA_B(cur, (ks+2)*32); // refill B[cur] (newest 3, spans fence)
    __builtin_amdgcn_s_setprio(1);
    #pragma unroll
    for(int rt=0;rt<8;rt++){
      #pragma unroll
      for(int g=0;g<5;g++)
        acc[g][rt] = __builtin_amdgcn_mfma_f32_16x16x32_bf16(afrag[rt], bfrag[g], acc[g][rt], 0,0,0);
    }
    __builtin_amdgcn_s_setprio(0);
    if (ks < 30)       FENCE_VM(3);           // waits B[ks+1](3)+A[ks+1](2); keeps B[ks+2](3)
    else if (ks < 31)  FENCE_VM(0);           // tail: drain B31 + A31
  }

  const int j = nblk + wc*16 + lane16;
  const float bi =Uioub[j], bo=Uioub[512+j], bu=Uioub[1024+j];
  const float bfl=Ufb[j],   bfr=Ufb[512+j];
  #pragma unroll
  for(int rt=0;rt<8;rt++){
    #pragma unroll
    for(int reg=0;reg<4;reg++){
      const int row = mrow0 + wh*128 + rt*16 + quad*4 + reg;
      float iv=acc[0][rt][reg]+bi, ov=acc[1][rt][reg]+bo, uv=acc[2][rt][reg]+bu;
      float fl=acc[3][rt][reg]+bfl, fr=acc[4][rt][reg]+bfr;
      float cl = cprev[((size_t)row*2  )*512 + j];
      float cr = cprev[((size_t)row*2+1)*512 + j];
      float cf = sigm(fl)*cl + sigm(fr)*cr;
      float c  = sigm(iv)*tanh_f(uv) + cf;
      float h  = sigm(ov)*tanh_f(c);
      ccur[(size_t)row*512 + j] = c;
      hcur[(size_t)row*512 + j] = (bf16)h;
    }
  }
#undef LV256_DMA_A
#undef LV256_DMA_B
}

// ---- logits (verbatim GEMV, proven): single-level version for leaf chunks ----
__global__ __launch_bounds__(256)
void logits_kernel(const bf16* __restrict__ h, const float* __restrict__ linw,
                   const float* __restrict__ linb, float* __restrict__ out,
                   int rowbase, int lgm, int mask, int off){
  const int row = blockIdx.x*4 + (threadIdx.x>>6);
  const int l = threadIdx.x & 63;
  bf16x8 hv = *(const bf16x8*)(h + (size_t)row*512 + l*8);
  float hf[8];
  #pragma unroll
  for(int jj=0;jj<8;jj++) hf[jj] = (float)hv[jj];
  float s[5];
  #pragma unroll
  for(int c=0;c<5;c++){
    const f32x4 w0 = *(const f32x4*)(linw + c*512 + l*8);
    const f32x4 w1 = *(const f32x4*)(linw + c*512 + l*8 + 4);
    float a = 0.f;
    #pragma unroll
    for(int jj=0;jj<4;jj++) a += hf[jj]*w0[jj] + hf[4+jj]*w1[jj];
    s[c]=a;
  }
  #pragma unroll
  for(int o=32;o>0;o>>=1){
    #pragma unroll
    for(int c=0;c<5;c++) s[c] += __shfl_down(s[c], o, 64);
  }
  if (l==0){
    const int g = rowbase + row;
    const int node = (g>>lgm)*511 + off + (g&mask);
    #pragma unroll
    for(int c=0;c<5;c++) out[(size_t)node*5+c] = s[c] + linb[c];
  }
}

// ---- logits2: two levels in one dispatch (same GEMV; per-row source select) ----
__global__ __launch_bounds__(256)
void logits2_kernel(const bf16* __restrict__ ha, int rows_a, int lgm_a, int mask_a, int off_a,
                    const bf16* __restrict__ hb, int lgm_b, int mask_b, int off_b,
                    const float* __restrict__ linw, const float* __restrict__ linb,
                    float* __restrict__ out){
  const int row = blockIdx.x*4 + (threadIdx.x>>6);
  const int l = threadIdx.x & 63;
  const bf16* hrow; int g, lgm, mask, off;
  if (row < rows_a){ hrow = ha + (size_t)row*512;            g = row;           lgm=lgm_a; mask=mask_a; off=off_a; }
  else             { hrow = hb + (size_t)(row-rows_a)*512;   g = row - rows_a;  lgm=lgm_b; mask=mask_b; off=off_b; }
  bf16x8 hv = *(const bf16x8*)(hrow + l*8);
  float hf[8];
  #pragma unroll
  for(int jj=0;jj<8;jj++) hf[jj] = (float)hv[jj];
  float s[5];
  #pragma unroll
  for(int c=0;c<5;c++){
    const f32x4 w0 = *(const f32x4*)(linw + c*512 + l*8);
    const f32x4 w1 = *(const f32x4*)(linw + c*512 + l*8 + 4);
    float a = 0.f;
    #pragma unroll
    for(int jj=0;jj<4;jj++) a += hf[jj]*w0[jj] + hf[4+jj]*w1[jj];
    s[c]=a;
  }
  #pragma unroll
  for(int o=32;o>0;o>>=1){
    #pragma unroll
    for(int c=0;c<5;c++) s[c] += __shfl_down(s[c], o, 64);
  }
  if (l==0){
    const int node = (g>>lgm)*511 + off + (g&mask);
    #pragma unroll
    for(int c=0;c<5;c++) out[(size_t)node*5+c] = s[c] + linb[c];
  }
}

__global__ void zero_out(float* out, int n){
  int i = blockIdx.x*256 + threadIdx.x;
  if (i < n) out[i] = 0.f;
}

extern "C" void kernel_launch(void* const* d_in, const int* in_sizes, int n_in,
                              void* d_out, int out_size, void* d_ws, size_t ws_size,
                              hipStream_t stream)
{
  const int*   wordid = (const int*)d_in[0];
  const float* emb    = (const float*)d_in[1];
  const float* Wiou   = (const float*)d_in[2];
  const float* Wioub  = (const float*)d_in[3];
  const float* Uiou   = (const float*)d_in[4];
  const float* Uioub  = (const float*)d_in[5];
  const float* Uf     = (const float*)d_in[6];
  const float* Ufb    = (const float*)d_in[7];
  const float* linw   = (const float*)d_in[8];
  const float* linb   = (const float*)d_in[9];
  float* out = (float*)d_out;

  // ---- fixed-region layout (R7/R14) ----
  const size_t oWPD  = 0;
  const size_t oUALL = oWPD  + (size_t)1536*320*2;
  const size_t oEMB  = oUALL + (size_t)2560*1024*2;
  const size_t oH1   = oEMB  + (size_t)32000*320*2;
  const size_t oC1   = oH1   + (size_t)32768*512*2;
  const size_t oH0   = oC1   + (size_t)32768*512*4;
  size_t R0 = 0;
  {
    const size_t t2 = oH0 + (size_t)32768*512*(2+4);   // 228.0 MB
    const size_t t4 = oH0 + (size_t)16384*512*(2+4);   // 177.7 MB
    const size_t t8 = oH0 + (size_t) 8192*512*(2+4);   // 152.5 MB
    if      (ws_size >= t2) R0 = 32768;
    else if (ws_size >= t4) R0 = 16384;
    else if (ws_size >= t8) R0 = 8192;
  }
  if (R0 == 0){
    zero_out<<<(out_size+255)/256, 256, 0, stream>>>(out, out_size);
    return;
  }

  char* ws = (char*)d_ws;
  bf16*  Wpad = (bf16*)(ws + oWPD);
  bf16*  Uall = (bf16*)(ws + oUALL);
  bf16*  embp = (bf16*)(ws + oEMB);
  bf16*  h1   = (bf16*)(ws + oH1);
  float* c1   = (float*)(ws + oC1);
  bf16*  h0   = (bf16*)(ws + oH0);
  float* c0   = (float*)(ws + oH0 + R0*1024);

  // 122880 + 2560000 + 655360 = 3,338,240 vec4 tasks = 13040 blocks * 256
  cvt_all<<<13040, 256, 0, stream>>>(Wiou, Uiou, Uf, emb, Wpad, Uall, embp);

  const int offs[9] = {0,256,384,448,480,496,504,508,510};
  const int nchunk = (int)(65536 / R0);

  // ---- leaf + level-1, chunked through h0/c0 scratch (leaf logits per chunk) ----
  for (int ch = 0; ch < nchunk; ch++){
    const int* wid = wordid + (size_t)ch*R0;
    leaf128_kernel<<<dim3((int)(R0/128), 8), 256, 0, stream>>>(wid, embp, Wpad, Wioub,
                                                               h0, c0);
    logits_kernel<<<(int)(R0/4), 256, 0, stream>>>(h0, linw, linb, out,
                                                   (int)(ch*R0), 8, 255, 0);
    bf16*  h1c = h1 + (size_t)ch*(R0/2)*512;
    float* c1c = c1 + (size_t)ch*(R0/2)*512;
    const int orows = (int)(R0/2);
    if (orows >= 8192)
      level256_kernel<<<dim3(orows/256, 8), 512, 0, stream>>>(h0, h1c, c0, c1c,
                                                              Uall, Uioub, Ufb);
    else
      level_kernel<<<dim3(orows/64, 8), 256, 0, stream>>>(h0, h1c, c0, c1c,
                                                          Uall, Uioub, Ufb);
  }

  // ---- levels 2..8; after each EVEN level, one logits2 covers (lv-1, lv) ----
  // Validity: lv-1's h (h1) is intact until lv+1 writes h1; lv's h (h0) until lv+2.
  for (int lv = 2; lv <= 8; lv++){
    const int rows = 65536 >> lv;
    const bf16*  hin  = (lv & 1) ? h0 : h1;
    bf16*        hout = (lv & 1) ? h1 : h0;
    const float* cin  = (lv & 1) ? c0 : c1;
    float*       cout = (lv & 1) ? c1 : c0;
    if (rows >= 8192)
      level256_kernel<<<dim3(rows/256, 8), 512, 0, stream>>>(hin, hout, cin, cout,
                                                             Uall, Uioub, Ufb);
    else
      level_kernel<<<dim3(rows/64, 8), 256, 0, stream>>>(hin, hout, cin, cout,
                                                         Uall, Uioub, Ufb);
    if ((lv & 1) == 0){
      const int rows_a = 65536 >> (lv-1);        // lv-1 rows (in h1)
      const int rows_b = rows;                   // lv rows   (in h0)
      logits2_kernel<<<(rows_a + rows_b)/4, 256, 0, stream>>>(
          h1, rows_a, 8-(lv-1), (256>>(lv-1))-1, offs[lv-1],
          h0,         8-lv,     (256>>lv)-1,     offs[lv],
          linw, linb, out);
    }
  }
}